// Round 4
// baseline (474.532 us; speedup 1.0000x reference)
//
#include <hip/hip_runtime.h>

#define Bb 16
#define Hh 256
#define Ll 4096
#define KDIM 32
#define NFFT 8192

// ws layout (needs >= 56 MB):
//   [0x0000000, 0x0400000) k_norm f32 [256][4096]          (4 MB)
//   [0x0400000, 0x0408000) tw float2[4096]                 (32 KB)
//   [0x0410000, 0x0450000) Wt f32 [256][256] (Wt[h][h'])   (256 KB)
//   [0x0800000, 0x1800000) Kst float2 [256][8192]          (16 MB)
//   [0x1800000, 0x3800000) g bf16 [16][256][4096]          (32 MB)

static __device__ __forceinline__ unsigned short f2bf(float f) {
  unsigned u = __float_as_uint(f);
  u += 0x7FFFu + ((u >> 16) & 1u);
  return (unsigned short)(u >> 16);
}

// ---------------- setup: build normalized k, twiddles, W^T ----------------
__global__ void __launch_bounds__(256) gconv_setup(
    const float* __restrict__ kernels,  // [8][1][256][32]
    const float* __restrict__ W_out,    // [256][256]
    float* __restrict__ k_norm,         // [256][4096]
    float2* __restrict__ tw,            // [4096]
    float* __restrict__ Wt)             // [256][256]
{
  int blk = blockIdx.x;
  int tid = threadIdx.x;
  if (blk < 256) {
    int h = blk;
    __shared__ float red[256];
    float val[16];
    float ss = 0.0f;
#pragma unroll
    for (int r = 0; r < 16; ++r) {
      int l = tid + 256 * r;
      int i;
      if (l < 32) i = 0;
      else if (l < 64) i = 1;
      else i = (31 - __clz(l)) - 4;           // l in [64,128)->2 ... [2048,4096)->7
      int off = (i == 0) ? 0 : (16 << i);     // 0,32,64,128,...,2048
      int s = (i <= 1) ? 1 : (1 << (i - 1));  // 1,1,2,4,...,64
      float mult = (float)(1 << (7 - i));
      int j = l - off;
      const float* kb = kernels + ((size_t)i * Hh + h) * KDIM;
      float v;
      if (s == 1) {
        v = kb[j];
      } else {
        float x = ((float)j + 0.5f) / (float)s - 0.5f;
        x = fminf(fmaxf(x, 0.0f), 31.0f);
        float xf = floorf(x);
        int x0 = (int)xf;
        int x1 = min(x0 + 1, 31);
        float w = x - xf;
        v = kb[x0] * (1.0f - w) + kb[x1] * w;
      }
      v *= mult;
      val[r] = v;
      ss += v * v;
    }
    red[tid] = ss;
    __syncthreads();
    for (int o = 128; o > 0; o >>= 1) {
      if (tid < o) red[tid] += red[tid + o];
      __syncthreads();
    }
    float inv = 1.0f / sqrtf(red[0]);
#pragma unroll
    for (int r = 0; r < 16; ++r)
      k_norm[(size_t)h * Ll + tid + 256 * r] = val[r] * inv;
  } else if (blk < 272) {
    int idx = (blk - 256) * 256 + tid;  // 0..4095
    double ang = -6.283185307179586477 * (double)idx / 8192.0;
    tw[idx] = make_float2((float)cos(ang), (float)sin(ang));
  } else {
    int o = (blk - 272) * 256 + tid;    // 0..65535 ; Wt[h][h'] = W_out[h'][h]
    Wt[o] = W_out[(o & 255) * 256 + (o >> 8)];
  }
}

// ---------------- kernel FFT: K_hat = DIF(pad(k)) ; fold D and 1/N --------
__global__ void __launch_bounds__(512) gconv_kfft(
    const float* __restrict__ k_norm,
    const float* __restrict__ Dvec,     // [256]
    const float2* __restrict__ tw,
    float2* __restrict__ Kst)           // [256][8192]
{
  __shared__ float re[NFFT];
  __shared__ float im[NFFT];
  int h = blockIdx.x;
  int tid = threadIdx.x;
  for (int n = tid; n < 4096; n += 512) { re[n] = k_norm[(size_t)h * Ll + n]; im[n] = 0.0f; }
  for (int n = 4096 + tid; n < NFFT; n += 512) { re[n] = 0.0f; im[n] = 0.0f; }
  __syncthreads();
  for (int logh = 12; logh >= 0; --logh) {
    int hh = 1 << logh;
    for (int t = tid; t < 4096; t += 512) {
      int j = t & (hh - 1);
      int i0 = ((t >> logh) << (logh + 1)) + j;
      int i1 = i0 + hh;
      float ar = re[i0], ai = im[i0], br = re[i1], bi = im[i1];
      re[i0] = ar + br; im[i0] = ai + bi;
      float2 w = tw[j << (12 - logh)];
      float dr = ar - br, di = ai - bi;
      re[i1] = dr * w.x - di * w.y;
      im[i1] = dr * w.y + di * w.x;
    }
    __syncthreads();
  }
  float Dh = Dvec[h];
  const float sc = 1.0f / 8192.0f;
  for (int n = tid; n < NFFT; n += 512)
    Kst[(size_t)h * NFFT + n] = make_float2((re[n] + Dh) * sc, im[n] * sc);
}

// ---------------- main: fwd FFT (b-pair packed), multiply, inv FFT, gelu --
__global__ void __launch_bounds__(512) gconv_main(
    const float* __restrict__ u,
    const float2* __restrict__ tw,
    const float2* __restrict__ Kst,
    unsigned short* __restrict__ g)     // bf16 [16][256][4096]
{
  __shared__ float re[NFFT];
  __shared__ float im[NFFT];
  int blk = blockIdx.x;
  int h = blk & 255;
  int pb = blk >> 8;      // 0..7
  int b0 = pb, b1 = pb + 8;
  int tid = threadIdx.x;
  const float* u0 = u + ((size_t)(b0 * Hh + h)) * Ll;
  const float* u1 = u + ((size_t)(b1 * Hh + h)) * Ll;
  for (int q = tid; q < 1024; q += 512) {
    float4 a = ((const float4*)u0)[q];
    float4 b = ((const float4*)u1)[q];
    ((float4*)re)[q] = a;
    ((float4*)im)[q] = b;
  }
  for (int n = 4096 + tid; n < NFFT; n += 512) { re[n] = 0.0f; im[n] = 0.0f; }
  __syncthreads();
  // forward DIF (natural in -> bit-reversed out)
  for (int logh = 12; logh >= 0; --logh) {
    int hh = 1 << logh;
    for (int t = tid; t < 4096; t += 512) {
      int j = t & (hh - 1);
      int i0 = ((t >> logh) << (logh + 1)) + j;
      int i1 = i0 + hh;
      float ar = re[i0], ai = im[i0], br = re[i1], bi = im[i1];
      re[i0] = ar + br; im[i0] = ai + bi;
      float2 w = tw[j << (12 - logh)];
      float dr = ar - br, di = ai - bi;
      re[i1] = dr * w.x - di * w.y;
      im[i1] = dr * w.y + di * w.x;
    }
    __syncthreads();
  }
  // pointwise multiply by K_hat (same permuted order; D and 1/N folded in)
  const float2* kr = Kst + (size_t)h * NFFT;
  for (int n = tid; n < NFFT; n += 512) {
    float2 kv = kr[n];
    float zr = re[n], zi = im[n];
    re[n] = zr * kv.x - zi * kv.y;
    im[n] = zr * kv.y + zi * kv.x;
  }
  __syncthreads();
  // inverse DIT with conjugate twiddles (bit-reversed in -> natural out)
  for (int logh = 0; logh <= 12; ++logh) {
    int hh = 1 << logh;
    for (int t = tid; t < 4096; t += 512) {
      int j = t & (hh - 1);
      int i0 = ((t >> logh) << (logh + 1)) + j;
      int i1 = i0 + hh;
      float2 w = tw[j << (12 - logh)];
      float br = re[i1], bi = im[i1];
      float tr = br * w.x + bi * w.y;   // b * conj(w)
      float ti = bi * w.x - br * w.y;
      float ar = re[i0], ai = im[i0];
      re[i0] = ar + tr; im[i0] = ai + ti;
      re[i1] = ar - tr; im[i1] = ai - ti;
    }
    __syncthreads();
  }
  // gelu(exact) + store bf16
  int l0 = tid * 8;
  union { unsigned short us[8]; uint4 v; } o0, o1;
#pragma unroll
  for (int q = 0; q < 8; ++q) {
    float y0 = re[l0 + q], y1 = im[l0 + q];
    y0 = 0.5f * y0 * (1.0f + erff(y0 * 0.70710678118654752f));
    y1 = 0.5f * y1 * (1.0f + erff(y1 * 0.70710678118654752f));
    o0.us[q] = f2bf(y0); o1.us[q] = f2bf(y1);
  }
  *(uint4*)(g + ((size_t)(b0 * Hh + h)) * Ll + l0) = o0.v;
  *(uint4*)(g + ((size_t)(b1 * Hh + h)) * Ll + l0) = o1.v;
}

// ---------------- output projection: out = W @ g + b ----------------------
__global__ void __launch_bounds__(256) gconv_out(
    const unsigned short* __restrict__ g,   // bf16 [16][256][4096]
    const float* __restrict__ Wt,           // [k=256][m=256]
    const float* __restrict__ b_out,        // [256]
    float* __restrict__ out)                // [16][256][4096]
{
  __shared__ float As[16][128];
  __shared__ unsigned short Bs[16][128];
  int nt = blockIdx.x;        // 32 l-tiles
  int mt = blockIdx.y;        // 2 m-tiles
  int b  = blockIdx.z;        // 16
  int l0 = nt * 128, m0 = mt * 128;
  int tid = threadIdx.x;
  int tx = tid & 15, ty = tid >> 4;
  float acc[8][8];
#pragma unroll
  for (int ii = 0; ii < 8; ++ii)
#pragma unroll
    for (int jj = 0; jj < 8; ++jj) acc[ii][jj] = 0.0f;

  for (int kc = 0; kc < 16; ++kc) {
#pragma unroll
    for (int q = 0; q < 2; ++q) {
      int qq = tid + q * 256;
      int row = qq >> 5, c4 = qq & 31;
      ((float4*)&As[row][0])[c4] =
          *(const float4*)(Wt + (size_t)(kc * 16 + row) * 256 + m0 + c4 * 4);
    }
    {
      int row = tid >> 4, c8 = tid & 15;
      ((uint4*)&Bs[row][0])[c8] =
          *(const uint4*)(g + ((size_t)(b * Hh + kc * 16 + row)) * Ll + l0 + c8 * 8);
    }
    __syncthreads();
#pragma unroll
    for (int k = 0; k < 16; ++k) {
      float a[8];
      ((float4*)a)[0] = *(const float4*)&As[k][ty * 8];
      ((float4*)a)[1] = *(const float4*)&As[k][ty * 8 + 4];
      uint4 bp = *(const uint4*)&Bs[k][tx * 8];
      float bb[8];
      bb[0] = __uint_as_float(bp.x << 16);
      bb[1] = __uint_as_float(bp.x & 0xFFFF0000u);
      bb[2] = __uint_as_float(bp.y << 16);
      bb[3] = __uint_as_float(bp.y & 0xFFFF0000u);
      bb[4] = __uint_as_float(bp.z << 16);
      bb[5] = __uint_as_float(bp.z & 0xFFFF0000u);
      bb[6] = __uint_as_float(bp.w << 16);
      bb[7] = __uint_as_float(bp.w & 0xFFFF0000u);
#pragma unroll
      for (int ii = 0; ii < 8; ++ii)
#pragma unroll
        for (int jj = 0; jj < 8; ++jj) acc[ii][jj] += a[ii] * bb[jj];
    }
    __syncthreads();
  }
#pragma unroll
  for (int ii = 0; ii < 8; ++ii) {
    int m = m0 + ty * 8 + ii;
    float bias = b_out[m];
    float* op = out + ((size_t)(b * Hh + m)) * Ll + l0 + tx * 8;
    float4 v0 = make_float4(acc[ii][0] + bias, acc[ii][1] + bias,
                            acc[ii][2] + bias, acc[ii][3] + bias);
    float4 v1 = make_float4(acc[ii][4] + bias, acc[ii][5] + bias,
                            acc[ii][6] + bias, acc[ii][7] + bias);
    ((float4*)op)[0] = v0;
    ((float4*)op)[1] = v1;
  }
}

extern "C" void kernel_launch(void* const* d_in, const int* in_sizes, int n_in,
                              void* d_out, int out_size, void* d_ws, size_t ws_size,
                              hipStream_t stream) {
  (void)in_sizes; (void)n_in; (void)out_size; (void)ws_size;
  const float* u       = (const float*)d_in[0];
  const float* kernels = (const float*)d_in[1];
  const float* Dvec    = (const float*)d_in[2];
  const float* W_out   = (const float*)d_in[3];
  const float* b_out   = (const float*)d_in[4];
  float* out = (float*)d_out;
  char* ws = (char*)d_ws;

  float*  k_norm = (float*)(ws);
  float2* tw     = (float2*)(ws + (4u << 20));
  float*  Wt     = (float*)(ws + (4u << 20) + (64u << 10));
  float2* Kst    = (float2*)(ws + (8u << 20));
  unsigned short* g = (unsigned short*)(ws + (24u << 20));

  gconv_setup<<<528, 256, 0, stream>>>(kernels, W_out, k_norm, tw, Wt);
  gconv_kfft<<<256, 512, 0, stream>>>(k_norm, Dvec, tw, Kst);
  gconv_main<<<2048, 512, 0, stream>>>(u, tw, Kst, g);
  dim3 gd(32, 2, 16);
  gconv_out<<<gd, 256, 0, stream>>>(g, Wt, b_out, out);
}

// Round 5
// 345.436 us; speedup vs baseline: 1.3737x; 1.3737x over previous
//
#include <hip/hip_runtime.h>

#define NFFT 8192

// ws layout (needs >= 56 MB):
//   [0x0000000, 0x0400000) k_norm f32 [256][4096]            (4 MB)
//   [0x0400000, 0x0410000) tw8k float2[8192]                 (64 KB)
//   [0x0420000, 0x0460000) Wt f32 [256][256] (Wt[h][h'])     (256 KB)
//   [0x0800000, 0x1800000) Kst float2 [256][8192]            (16 MB)
//   [0x1800000, 0x3800000) g bf16 [16][256][4096]            (32 MB)

#define C1f 0.92387953251128674f
#define S1f 0.38268343236508977f
#define C2f 0.70710678118654752f

static __device__ __forceinline__ unsigned short f2bf(float f) {
  unsigned u = __float_as_uint(f);
  u += 0x7FFFu + ((u >> 16) & 1u);
  return (unsigned short)(u >> 16);
}

static __device__ __forceinline__ void cmul(float& ar, float& ai, float br, float bi) {
  float t = ar * br - ai * bi;
  ai = ar * bi + ai * br;
  ar = t;
}

// forward 16-pt DFT, DIF radix-2, in-place; output slot p holds X[rev4(p)]
static __device__ __forceinline__ void dft16_fwd(float* xr, float* xi) {
  const float wr[8] = {1.f, C1f, C2f, S1f, 0.f, -S1f, -C2f, -C1f};
  const float wi[8] = {0.f, -S1f, -C2f, -C1f, -1.f, -C1f, -C2f, -S1f};
  // L1 span 8, tw w16^j
#pragma unroll
  for (int j = 0; j < 8; ++j) {
    float ar = xr[j], ai = xi[j], br = xr[j + 8], bi = xi[j + 8];
    xr[j] = ar + br; xi[j] = ai + bi;
    float dr = ar - br, di = ai - bi;
    xr[j + 8] = dr * wr[j] - di * wi[j];
    xi[j + 8] = dr * wi[j] + di * wr[j];
  }
  // L2 span 4, tw w16^{2j}
#pragma unroll
  for (int h = 0; h < 2; ++h) {
#pragma unroll
    for (int j = 0; j < 4; ++j) {
      int i0 = h * 8 + j, i1 = i0 + 4;
      float ar = xr[i0], ai = xi[i0], br = xr[i1], bi = xi[i1];
      xr[i0] = ar + br; xi[i0] = ai + bi;
      float dr = ar - br, di = ai - bi;
      xr[i1] = dr * wr[2 * j] - di * wi[2 * j];
      xi[i1] = dr * wi[2 * j] + di * wr[2 * j];
    }
  }
  // L3 span 2: j=0 plain; j=1 tw (0,-1): (dr,di)->(di,-dr)
#pragma unroll
  for (int h = 0; h < 4; ++h) {
    int base = h * 4;
    {
      int i0 = base, i1 = base + 2;
      float ar = xr[i0], ai = xi[i0], br = xr[i1], bi = xi[i1];
      xr[i0] = ar + br; xi[i0] = ai + bi;
      xr[i1] = ar - br; xi[i1] = ai - bi;
    }
    {
      int i0 = base + 1, i1 = base + 3;
      float ar = xr[i0], ai = xi[i0], br = xr[i1], bi = xi[i1];
      xr[i0] = ar + br; xi[i0] = ai + bi;
      float dr = ar - br, di = ai - bi;
      xr[i1] = di; xi[i1] = -dr;
    }
  }
  // L4 span 1, tw 1
#pragma unroll
  for (int h = 0; h < 8; ++h) {
    int i0 = h * 2, i1 = i0 + 1;
    float ar = xr[i0], ai = xi[i0], br = xr[i1], bi = xi[i1];
    xr[i0] = ar + br; xi[i0] = ai + bi;
    xr[i1] = ar - br; xi[i1] = ai - bi;
  }
}

// inverse 16-pt DFT (conjugate mirror of dft16_fwd, no 1/16 scaling);
// input slot p = X[rev4(p)], output natural order
static __device__ __forceinline__ void dft16_inv(float* xr, float* xi) {
  const float wr[8] = {1.f, C1f, C2f, S1f, 0.f, -S1f, -C2f, -C1f};
  const float wi[8] = {0.f, S1f, C2f, C1f, 1.f, C1f, C2f, S1f};  // conj
  // L4' span 1
#pragma unroll
  for (int h = 0; h < 8; ++h) {
    int i0 = h * 2, i1 = i0 + 1;
    float ar = xr[i0], ai = xi[i0], br = xr[i1], bi = xi[i1];
    xr[i0] = ar + br; xi[i0] = ai + bi;
    xr[i1] = ar - br; xi[i1] = ai - bi;
  }
  // L3' span 2: j=0 plain; j=1: t = b*(0,1) = (-bi, br)
#pragma unroll
  for (int h = 0; h < 4; ++h) {
    int base = h * 4;
    {
      int i0 = base, i1 = base + 2;
      float ar = xr[i0], ai = xi[i0], tr = xr[i1], ti = xi[i1];
      xr[i0] = ar + tr; xi[i0] = ai + ti;
      xr[i1] = ar - tr; xi[i1] = ai - ti;
    }
    {
      int i0 = base + 1, i1 = base + 3;
      float ar = xr[i0], ai = xi[i0], br = xr[i1], bi = xi[i1];
      float tr = -bi, ti = br;
      xr[i0] = ar + tr; xi[i0] = ai + ti;
      xr[i1] = ar - tr; xi[i1] = ai - ti;
    }
  }
  // L2' span 4
#pragma unroll
  for (int h = 0; h < 2; ++h) {
#pragma unroll
    for (int j = 0; j < 4; ++j) {
      int i0 = h * 8 + j, i1 = i0 + 4;
      float br = xr[i1], bi = xi[i1];
      float tr = br * wr[2 * j] - bi * wi[2 * j];
      float ti = br * wi[2 * j] + bi * wr[2 * j];
      float ar = xr[i0], ai = xi[i0];
      xr[i0] = ar + tr; xi[i0] = ai + ti;
      xr[i1] = ar - tr; xi[i1] = ai - ti;
    }
  }
  // L1' span 8
#pragma unroll
  for (int j = 0; j < 8; ++j) {
    int i0 = j, i1 = j + 8;
    float br = xr[i1], bi = xi[i1];
    float tr = br * wr[j] - bi * wi[j];
    float ti = br * wi[j] + bi * wr[j];
    float ar = xr[i0], ai = xi[i0];
    xr[i0] = ar + tr; xi[i0] = ai + ti;
    xr[i1] = ar - tr; xi[i1] = ai - ti;
  }
}

#define REV_INIT constexpr int REV[16] = {0, 8, 4, 12, 2, 10, 6, 14, 1, 9, 5, 13, 3, 11, 7, 15}

// 8192-pt forward FFT across 512 threads; thread t enters with reg slot m
// holding x[t + 512 m] (natural); exits with slot j holding spectral value at
// permuted position P(t,j) = (t>>1)*32 + (t&1) + 2*rev4(j).
static __device__ __forceinline__ void fft8192_fwd(float* xr, float* xi, float* lre,
                                                   float* lim, int t,
                                                   const float2* __restrict__ tw8k) {
  REV_INIT;
  // S1: radix-16, stride 512, group q = t
  dft16_fwd(xr, xi);
#pragma unroll
  for (int j = 1; j < 16; ++j) {
    float2 w = tw8k[REV[j] * t];
    cmul(xr[j], xi[j], w.x, w.y);
  }
#pragma unroll
  for (int j = 0; j < 16; ++j) {
    int p = t + (REV[j] << 9);
    p += p >> 5;
    lre[p] = xr[j]; lim[p] = xi[j];
  }
  __syncthreads();
  // S2: radix-16, stride 32, block b = t>>5, q' = t&31
  int base2 = ((t >> 5) << 9) + (t & 31);
  int q1 = t & 31;
#pragma unroll
  for (int m = 0; m < 16; ++m) {
    int p = base2 + (m << 5);
    p += p >> 5;
    xr[m] = lre[p]; xi[m] = lim[p];
  }
  dft16_fwd(xr, xi);
#pragma unroll
  for (int j = 1; j < 16; ++j) {
    float2 w = tw8k[(REV[j] * q1) << 4];
    cmul(xr[j], xi[j], w.x, w.y);
  }
#pragma unroll
  for (int j = 0; j < 16; ++j) {
    int p = base2 + (REV[j] << 5);
    p += p >> 5;
    lre[p] = xr[j]; lim[p] = xi[j];
  }
  __syncthreads();
  // S3: radix-16, stride 2, block c = t>>1, q'' = t&1
  int qq = t & 1;
  int base3 = ((t >> 1) << 5) + qq;
#pragma unroll
  for (int m = 0; m < 16; ++m) {
    int p = base3 + (m << 1);
    p += p >> 5;
    xr[m] = lre[p]; xi[m] = lim[p];
  }
  dft16_fwd(xr, xi);
  if (qq) {
#pragma unroll
    for (int j = 1; j < 16; ++j) {
      float2 w = tw8k[REV[j] << 8];
      cmul(xr[j], xi[j], w.x, w.y);
    }
  }
  // S4: radix-2 across lane pairs (no twiddle)
  float sgn = qq ? -1.f : 1.f;
#pragma unroll
  for (int j = 0; j < 16; ++j) {
    float pr = __shfl_xor(xr[j], 1);
    float pi = __shfl_xor(xi[j], 1);
    xr[j] = sgn * xr[j] + pr;
    xi[j] = sgn * xi[j] + pi;
  }
}

// exact inverse of fft8192_fwd (conjugate twiddles, mirrored stages);
// total scale 8192 is folded into Kst. Output: slot m = time sample t + 512 m.
static __device__ __forceinline__ void fft8192_inv(float* xr, float* xi, float* lre,
                                                   float* lim, int t,
                                                   const float2* __restrict__ tw8k) {
  REV_INIT;
  int qq = t & 1;
  float sgn = qq ? -1.f : 1.f;
  // iS4
#pragma unroll
  for (int j = 0; j < 16; ++j) {
    float pr = __shfl_xor(xr[j], 1);
    float pi = __shfl_xor(xi[j], 1);
    xr[j] = sgn * xr[j] + pr;
    xi[j] = sgn * xi[j] + pi;
  }
  // iS3
  if (qq) {
#pragma unroll
    for (int j = 1; j < 16; ++j) {
      float2 w = tw8k[REV[j] << 8];
      cmul(xr[j], xi[j], w.x, -w.y);
    }
  }
  dft16_inv(xr, xi);
  int base3 = ((t >> 1) << 5) + qq;
#pragma unroll
  for (int m = 0; m < 16; ++m) {
    int p = base3 + (m << 1);
    p += p >> 5;
    lre[p] = xr[m]; lim[p] = xi[m];
  }
  __syncthreads();
  // iS2
  int base2 = ((t >> 5) << 9) + (t & 31);
  int q1 = t & 31;
#pragma unroll
  for (int j = 0; j < 16; ++j) {
    int p = base2 + (REV[j] << 5);
    p += p >> 5;
    xr[j] = lre[p]; xi[j] = lim[p];
  }
#pragma unroll
  for (int j = 1; j < 16; ++j) {
    float2 w = tw8k[(REV[j] * q1) << 4];
    cmul(xr[j], xi[j], w.x, -w.y);
  }
  dft16_inv(xr, xi);
#pragma unroll
  for (int m = 0; m < 16; ++m) {
    int p = base2 + (m << 5);
    p += p >> 5;
    lre[p] = xr[m]; lim[p] = xi[m];
  }
  __syncthreads();
  // iS1
#pragma unroll
  for (int j = 0; j < 16; ++j) {
    int p = t + (REV[j] << 9);
    p += p >> 5;
    xr[j] = lre[p]; xi[j] = lim[p];
  }
#pragma unroll
  for (int j = 1; j < 16; ++j) {
    float2 w = tw8k[REV[j] * t];
    cmul(xr[j], xi[j], w.x, -w.y);
  }
  dft16_inv(xr, xi);
}

// ---------------- setup: build normalized k, twiddles, W^T ----------------
__global__ void __launch_bounds__(256) gconv_setup(
    const float* __restrict__ kernels,  // [8][1][256][32]
    const float* __restrict__ W_out,    // [256][256]
    float* __restrict__ k_norm,         // [256][4096]
    float2* __restrict__ tw8k,          // [8192]
    float* __restrict__ Wt)             // [256][256]
{
  int blk = blockIdx.x;
  int tid = threadIdx.x;
  if (blk < 256) {
    int h = blk;
    __shared__ float red[256];
    float val[16];
    float ss = 0.0f;
#pragma unroll
    for (int r = 0; r < 16; ++r) {
      int l = tid + 256 * r;
      int i;
      if (l < 32) i = 0;
      else if (l < 64) i = 1;
      else i = (31 - __clz(l)) - 4;
      int off = (i == 0) ? 0 : (16 << i);
      int s = (i <= 1) ? 1 : (1 << (i - 1));
      float mult = (float)(1 << (7 - i));
      int j = l - off;
      const float* kb = kernels + ((size_t)i * 256 + h) * 32;
      float v;
      if (s == 1) {
        v = kb[j];
      } else {
        float x = ((float)j + 0.5f) / (float)s - 0.5f;
        x = fminf(fmaxf(x, 0.0f), 31.0f);
        float xf = floorf(x);
        int x0 = (int)xf;
        int x1 = min(x0 + 1, 31);
        float w = x - xf;
        v = kb[x0] * (1.0f - w) + kb[x1] * w;
      }
      v *= mult;
      val[r] = v;
      ss += v * v;
    }
    red[tid] = ss;
    __syncthreads();
    for (int o = 128; o > 0; o >>= 1) {
      if (tid < o) red[tid] += red[tid + o];
      __syncthreads();
    }
    float inv = 1.0f / sqrtf(red[0]);
#pragma unroll
    for (int r = 0; r < 16; ++r)
      k_norm[(size_t)h * 4096 + tid + 256 * r] = val[r] * inv;
  } else if (blk < 288) {
    int idx = (blk - 256) * 256 + tid;  // 0..8191
    double ang = -6.283185307179586477 * (double)idx / 8192.0;
    tw8k[idx] = make_float2((float)cos(ang), (float)sin(ang));
  } else {
    int o = (blk - 288) * 256 + tid;    // 0..65535 ; Wt[h][h'] = W_out[h'][h]
    Wt[o] = W_out[(o & 255) * 256 + (o >> 8)];
  }
}

// ---------------- kernel FFT: K_hat (permuted layout), D and 1/N folded ---
__global__ void __launch_bounds__(512, 4) gconv_kfft(
    const float* __restrict__ k_norm,
    const float* __restrict__ Dvec,
    const float2* __restrict__ tw8k,
    float2* __restrict__ Kst)           // [256][8192], index h*8192 + t*16 + j
{
  __shared__ float lre[8448], lim[8448];
  int h = blockIdx.x;
  int t = threadIdx.x;
  float xr[16], xi[16];
  const float* kn = k_norm + ((size_t)h << 12);
#pragma unroll
  for (int m = 0; m < 8; ++m) { xr[m] = kn[t + (m << 9)]; xi[m] = 0.f; }
#pragma unroll
  for (int m = 8; m < 16; ++m) { xr[m] = 0.f; xi[m] = 0.f; }
  fft8192_fwd(xr, xi, lre, lim, t, tw8k);
  float Dh = Dvec[h];
  const float sc = 1.0f / 8192.0f;
  float2* out = Kst + ((size_t)h << 13) + (t << 4);
#pragma unroll
  for (int j = 0; j < 16; ++j)
    out[j] = make_float2((xr[j] + Dh) * sc, xi[j] * sc);
}

// ---------------- main: fwd FFT (b-pair packed), multiply, inv FFT, gelu --
__global__ void __launch_bounds__(512, 4) gconv_main(
    const float* __restrict__ u,
    const float2* __restrict__ tw8k,
    const float2* __restrict__ Kst,
    unsigned short* __restrict__ g)     // bf16 [16][256][4096]
{
  __shared__ float lre[8448], lim[8448];
  int blk = blockIdx.x;
  int h = blk & 255;
  int pb = blk >> 8;                    // 0..7 ; batches pb and pb+8
  int t = threadIdx.x;
  const float* u0 = u + ((size_t)(pb * 256 + h) << 12);
  const float* u1 = u + ((size_t)((pb + 8) * 256 + h) << 12);
  float xr[16], xi[16];
#pragma unroll
  for (int m = 0; m < 8; ++m) { xr[m] = u0[t + (m << 9)]; xi[m] = u1[t + (m << 9)]; }
#pragma unroll
  for (int m = 8; m < 16; ++m) { xr[m] = 0.f; xi[m] = 0.f; }
  fft8192_fwd(xr, xi, lre, lim, t, tw8k);
  // pointwise multiply in the shared permuted layout
  const float2* kr = Kst + ((size_t)h << 13) + (t << 4);
#pragma unroll
  for (int j = 0; j < 16; ++j) {
    float2 kv = kr[j];
    cmul(xr[j], xi[j], kv.x, kv.y);
  }
  fft8192_inv(xr, xi, lre, lim, t, tw8k);
  // gelu(exact) + store bf16 (keep first 4096 samples: m = 0..7)
  unsigned short* g0 = g + ((size_t)(pb * 256 + h) << 12) + t;
  unsigned short* g1 = g + ((size_t)((pb + 8) * 256 + h) << 12) + t;
#pragma unroll
  for (int m = 0; m < 8; ++m) {
    float y0 = xr[m], y1 = xi[m];
    y0 = 0.5f * y0 * (1.f + erff(y0 * 0.70710678118654752f));
    y1 = 0.5f * y1 * (1.f + erff(y1 * 0.70710678118654752f));
    g0[m << 9] = f2bf(y0);
    g1[m << 9] = f2bf(y1);
  }
}

// ---------------- output projection: out = W @ g + b ----------------------
__global__ void __launch_bounds__(256) gconv_out(
    const unsigned short* __restrict__ g,   // bf16 [16][256][4096]
    const float* __restrict__ Wt,           // [k=256][m=256]
    const float* __restrict__ b_out,        // [256]
    float* __restrict__ out)                // [16][256][4096]
{
  __shared__ float As[16][128];
  __shared__ unsigned short Bs[16][128];
  int nt = blockIdx.x;
  int mt = blockIdx.y;
  int b  = blockIdx.z;
  int l0 = nt * 128, m0 = mt * 128;
  int tid = threadIdx.x;
  int tx = tid & 15, ty = tid >> 4;
  float acc[8][8];
#pragma unroll
  for (int ii = 0; ii < 8; ++ii)
#pragma unroll
    for (int jj = 0; jj < 8; ++jj) acc[ii][jj] = 0.0f;

  for (int kc = 0; kc < 16; ++kc) {
#pragma unroll
    for (int q = 0; q < 2; ++q) {
      int qq = tid + q * 256;
      int row = qq >> 5, c4 = qq & 31;
      ((float4*)&As[row][0])[c4] =
          *(const float4*)(Wt + (size_t)(kc * 16 + row) * 256 + m0 + c4 * 4);
    }
    {
      int row = tid >> 4, c8 = tid & 15;
      ((uint4*)&Bs[row][0])[c8] =
          *(const uint4*)(g + ((size_t)(b * 256 + kc * 16 + row) << 12) + l0 + c8 * 8);
    }
    __syncthreads();
#pragma unroll
    for (int k = 0; k < 16; ++k) {
      float a[8];
      ((float4*)a)[0] = *(const float4*)&As[k][ty * 8];
      ((float4*)a)[1] = *(const float4*)&As[k][ty * 8 + 4];
      uint4 bp = *(const uint4*)&Bs[k][tx * 8];
      float bb[8];
      bb[0] = __uint_as_float(bp.x << 16);
      bb[1] = __uint_as_float(bp.x & 0xFFFF0000u);
      bb[2] = __uint_as_float(bp.y << 16);
      bb[3] = __uint_as_float(bp.y & 0xFFFF0000u);
      bb[4] = __uint_as_float(bp.z << 16);
      bb[5] = __uint_as_float(bp.z & 0xFFFF0000u);
      bb[6] = __uint_as_float(bp.w << 16);
      bb[7] = __uint_as_float(bp.w & 0xFFFF0000u);
#pragma unroll
      for (int ii = 0; ii < 8; ++ii)
#pragma unroll
        for (int jj = 0; jj < 8; ++jj) acc[ii][jj] += a[ii] * bb[jj];
    }
    __syncthreads();
  }
#pragma unroll
  for (int ii = 0; ii < 8; ++ii) {
    int m = m0 + ty * 8 + ii;
    float bias = b_out[m];
    float* op = out + ((size_t)(b * 256 + m) << 12) + l0 + tx * 8;
    float4 v0 = make_float4(acc[ii][0] + bias, acc[ii][1] + bias,
                            acc[ii][2] + bias, acc[ii][3] + bias);
    float4 v1 = make_float4(acc[ii][4] + bias, acc[ii][5] + bias,
                            acc[ii][6] + bias, acc[ii][7] + bias);
    ((float4*)op)[0] = v0;
    ((float4*)op)[1] = v1;
  }
}

extern "C" void kernel_launch(void* const* d_in, const int* in_sizes, int n_in,
                              void* d_out, int out_size, void* d_ws, size_t ws_size,
                              hipStream_t stream) {
  (void)in_sizes; (void)n_in; (void)out_size; (void)ws_size;
  const float* u       = (const float*)d_in[0];
  const float* kernels = (const float*)d_in[1];
  const float* Dvec    = (const float*)d_in[2];
  const float* W_out   = (const float*)d_in[3];
  const float* b_out   = (const float*)d_in[4];
  float* out = (float*)d_out;
  char* ws = (char*)d_ws;

  float*  k_norm = (float*)(ws);
  float2* tw8k   = (float2*)(ws + (4u << 20));
  float*  Wt     = (float*)(ws + (4u << 20) + (128u << 10));
  float2* Kst    = (float2*)(ws + (8u << 20));
  unsigned short* g = (unsigned short*)(ws + (24u << 20));

  gconv_setup<<<544, 256, 0, stream>>>(kernels, W_out, k_norm, tw8k, Wt);
  gconv_kfft<<<256, 512, 0, stream>>>(k_norm, Dvec, tw8k, Kst);
  gconv_main<<<2048, 512, 0, stream>>>(u, tw8k, Kst, g);
  dim3 gd(32, 2, 16);
  gconv_out<<<gd, 256, 0, stream>>>(g, Wt, b_out, out);
}

// Round 6
// 242.709 us; speedup vs baseline: 1.9551x; 1.4233x over previous
//
#include <hip/hip_runtime.h>

// ws layout (needs >= 56 MB):
//   [0x0000000, 0x0400000) k_norm f32 [256][4096]            (4 MB)
//   [0x0400000, 0x0401000) tw float2[512]                    (4 KB)
//   [0x0420000, 0x0460000) Wt f32 [256][256] (Wt[h][h'])     (256 KB)
//   [0x0800000, 0x1800000) Kst float2 [256][8192]            (16 MB)
//   [0x1800000, 0x3800000) g bf16 [16][256][4096]            (32 MB)

#define C1f 0.92387953251128674f
#define S1f 0.38268343236508977f
#define C2f 0.70710678118654752f

static __device__ __forceinline__ unsigned short f2bf(float f) {
  unsigned u = __float_as_uint(f);
  u += 0x7FFFu + ((u >> 16) & 1u);
  return (unsigned short)(u >> 16);
}

static __device__ __forceinline__ void cmul(float& ar, float& ai, float br, float bi) {
  float t = ar * br - ai * bi;
  ai = ar * bi + ai * br;
  ar = t;
}

// w32^k, k=0..15 (for S3 twiddles; forward uses -sin, inverse +sin)
__device__ __constant__ float W32C[16] = {
  1.f, 0.98078528040323044913f, 0.92387953251128675613f, 0.83146961230254523708f,
  0.70710678118654752440f, 0.55557023301960222474f, 0.38268343236508977173f,
  0.19509032201612826785f, 0.f, -0.19509032201612826785f, -0.38268343236508977173f,
  -0.55557023301960222474f, -0.70710678118654752440f, -0.83146961230254523708f,
  -0.92387953251128675613f, -0.98078528040323044913f};
__device__ __constant__ float W32S[16] = {
  0.f, 0.19509032201612826785f, 0.38268343236508977173f, 0.55557023301960222474f,
  0.70710678118654752440f, 0.83146961230254523708f, 0.92387953251128675613f,
  0.98078528040323044913f, 1.f, 0.98078528040323044913f, 0.92387953251128675613f,
  0.83146961230254523708f, 0.70710678118654752440f, 0.55557023301960222474f,
  0.38268343236508977173f, 0.19509032201612826785f};

// forward 16-pt DFT, DIF radix-2, in-place; output slot p holds X[rev4(p)]
static __device__ __forceinline__ void dft16_fwd(float* xr, float* xi) {
  const float wr[8] = {1.f, C1f, C2f, S1f, 0.f, -S1f, -C2f, -C1f};
  const float wi[8] = {0.f, -S1f, -C2f, -C1f, -1.f, -C1f, -C2f, -S1f};
#pragma unroll
  for (int j = 0; j < 8; ++j) {
    float ar = xr[j], ai = xi[j], br = xr[j + 8], bi = xi[j + 8];
    xr[j] = ar + br; xi[j] = ai + bi;
    float dr = ar - br, di = ai - bi;
    xr[j + 8] = dr * wr[j] - di * wi[j];
    xi[j + 8] = dr * wi[j] + di * wr[j];
  }
#pragma unroll
  for (int h = 0; h < 2; ++h) {
#pragma unroll
    for (int j = 0; j < 4; ++j) {
      int i0 = h * 8 + j, i1 = i0 + 4;
      float ar = xr[i0], ai = xi[i0], br = xr[i1], bi = xi[i1];
      xr[i0] = ar + br; xi[i0] = ai + bi;
      float dr = ar - br, di = ai - bi;
      xr[i1] = dr * wr[2 * j] - di * wi[2 * j];
      xi[i1] = dr * wi[2 * j] + di * wr[2 * j];
    }
  }
#pragma unroll
  for (int h = 0; h < 4; ++h) {
    int base = h * 4;
    {
      int i0 = base, i1 = base + 2;
      float ar = xr[i0], ai = xi[i0], br = xr[i1], bi = xi[i1];
      xr[i0] = ar + br; xi[i0] = ai + bi;
      xr[i1] = ar - br; xi[i1] = ai - bi;
    }
    {
      int i0 = base + 1, i1 = base + 3;
      float ar = xr[i0], ai = xi[i0], br = xr[i1], bi = xi[i1];
      xr[i0] = ar + br; xi[i0] = ai + bi;
      float dr = ar - br, di = ai - bi;
      xr[i1] = di; xi[i1] = -dr;
    }
  }
#pragma unroll
  for (int h = 0; h < 8; ++h) {
    int i0 = h * 2, i1 = i0 + 1;
    float ar = xr[i0], ai = xi[i0], br = xr[i1], bi = xi[i1];
    xr[i0] = ar + br; xi[i0] = ai + bi;
    xr[i1] = ar - br; xi[i1] = ai - bi;
  }
}

// inverse 16-pt DFT (conjugate mirror, no scaling); input slot p = X[rev4(p)]
static __device__ __forceinline__ void dft16_inv(float* xr, float* xi) {
  const float wr[8] = {1.f, C1f, C2f, S1f, 0.f, -S1f, -C2f, -C1f};
  const float wi[8] = {0.f, S1f, C2f, C1f, 1.f, C1f, C2f, S1f};
#pragma unroll
  for (int h = 0; h < 8; ++h) {
    int i0 = h * 2, i1 = i0 + 1;
    float ar = xr[i0], ai = xi[i0], br = xr[i1], bi = xi[i1];
    xr[i0] = ar + br; xi[i0] = ai + bi;
    xr[i1] = ar - br; xi[i1] = ai - bi;
  }
#pragma unroll
  for (int h = 0; h < 4; ++h) {
    int base = h * 4;
    {
      int i0 = base, i1 = base + 2;
      float ar = xr[i0], ai = xi[i0], tr = xr[i1], ti = xi[i1];
      xr[i0] = ar + tr; xi[i0] = ai + ti;
      xr[i1] = ar - tr; xi[i1] = ai - ti;
    }
    {
      int i0 = base + 1, i1 = base + 3;
      float ar = xr[i0], ai = xi[i0], br = xr[i1], bi = xi[i1];
      float tr = -bi, ti = br;
      xr[i0] = ar + tr; xi[i0] = ai + ti;
      xr[i1] = ar - tr; xi[i1] = ai - ti;
    }
  }
#pragma unroll
  for (int h = 0; h < 2; ++h) {
#pragma unroll
    for (int j = 0; j < 4; ++j) {
      int i0 = h * 8 + j, i1 = i0 + 4;
      float br = xr[i1], bi = xi[i1];
      float tr = br * wr[2 * j] - bi * wi[2 * j];
      float ti = br * wi[2 * j] + bi * wr[2 * j];
      float ar = xr[i0], ai = xi[i0];
      xr[i0] = ar + tr; xi[i0] = ai + ti;
      xr[i1] = ar - tr; xi[i1] = ai - ti;
    }
  }
#pragma unroll
  for (int j = 0; j < 8; ++j) {
    int i0 = j, i1 = j + 8;
    float br = xr[i1], bi = xi[i1];
    float tr = br * wr[j] - bi * wi[j];
    float ti = br * wi[j] + bi * wr[j];
    float ar = xr[i0], ai = xi[i0];
    xr[i0] = ar + tr; xi[i0] = ai + ti;
    xr[i1] = ar - tr; xi[i1] = ai - ti;
  }
}

#define REV_INIT constexpr int REV[16] = {0, 8, 4, 12, 2, 10, 6, 14, 1, 9, 5, 13, 3, 11, 7, 15}

// apply slot-j twiddle w^(REV[j]) by power chain from base (cr,ci); REV is an involution
#define TWCHAIN(XR, XI, CR, CI)                         \
  {                                                     \
    float pr_ = (CR), pi_ = (CI);                       \
    cmul(XR[8], XI[8], pr_, pi_);                       \
    _Pragma("unroll") for (int k = 2; k < 16; ++k) {    \
      cmul(pr_, pi_, (CR), (CI));                       \
      cmul(XR[REV[k]], XI[REV[k]], pr_, pi_);           \
    }                                                   \
  }

// 8192-pt forward FFT across 512 threads; thread t enters with reg slot m
// holding x[t + 512 m] (natural); exits with slot j holding spectral value at
// permuted position P(t,j) = (t>>1)*32 + (t&1) + 2*rev4(j).
// lbuf: 8448 floats; boundaries are re-pass then im-pass (3 barriers each).
static __device__ __forceinline__ void fft8192_fwd(float* xr, float* xi, float* lbuf,
                                                   int t, const float2* __restrict__ tw) {
  REV_INIT;
  // S1: radix-16, stride 512
  dft16_fwd(xr, xi);
  {
    float2 w1 = tw[t];
    TWCHAIN(xr, xi, w1.x, w1.y);
  }
  // B1
  int base2 = ((t >> 5) << 9) + (t & 31);
#pragma unroll
  for (int j = 0; j < 16; ++j) { int p = t + (REV[j] << 9); p += p >> 5; lbuf[p] = xr[j]; }
  __syncthreads();
#pragma unroll
  for (int m = 0; m < 16; ++m) { int p = base2 + (m << 5); p += p >> 5; xr[m] = lbuf[p]; }
  __syncthreads();
#pragma unroll
  for (int j = 0; j < 16; ++j) { int p = t + (REV[j] << 9); p += p >> 5; lbuf[p] = xi[j]; }
  __syncthreads();
#pragma unroll
  for (int m = 0; m < 16; ++m) { int p = base2 + (m << 5); p += p >> 5; xi[m] = lbuf[p]; }
  // S2: radix-16, stride 32
  dft16_fwd(xr, xi);
  {
    float2 w1 = tw[(t & 31) << 4];
    TWCHAIN(xr, xi, w1.x, w1.y);
  }
  // B2
  int qq = t & 1;
  int base3 = ((t >> 1) << 5) + qq;
#pragma unroll
  for (int j = 0; j < 16; ++j) { int p = base2 + (REV[j] << 5); p += p >> 5; lbuf[p] = xr[j]; }
  __syncthreads();
#pragma unroll
  for (int m = 0; m < 16; ++m) { int p = base3 + (m << 1); p += p >> 5; xr[m] = lbuf[p]; }
  __syncthreads();
#pragma unroll
  for (int j = 0; j < 16; ++j) { int p = base2 + (REV[j] << 5); p += p >> 5; lbuf[p] = xi[j]; }
  __syncthreads();
#pragma unroll
  for (int m = 0; m < 16; ++m) { int p = base3 + (m << 1); p += p >> 5; xi[m] = lbuf[p]; }
  // S3: radix-16, stride 2
  dft16_fwd(xr, xi);
  if (qq) {
#pragma unroll
    for (int k = 1; k < 16; ++k) cmul(xr[REV[k]], xi[REV[k]], W32C[k], -W32S[k]);
  }
  // S4: radix-2 across lane pairs
  float sgn = qq ? -1.f : 1.f;
#pragma unroll
  for (int j = 0; j < 16; ++j) {
    float pr = __shfl_xor(xr[j], 1);
    float pi = __shfl_xor(xi[j], 1);
    xr[j] = sgn * xr[j] + pr;
    xi[j] = sgn * xi[j] + pi;
  }
}

// exact inverse (conjugate twiddles, mirrored); scale 8192 folded into Kst.
static __device__ __forceinline__ void fft8192_inv(float* xr, float* xi, float* lbuf,
                                                   int t, const float2* __restrict__ tw) {
  REV_INIT;
  int qq = t & 1;
  float sgn = qq ? -1.f : 1.f;
#pragma unroll
  for (int j = 0; j < 16; ++j) {
    float pr = __shfl_xor(xr[j], 1);
    float pi = __shfl_xor(xi[j], 1);
    xr[j] = sgn * xr[j] + pr;
    xi[j] = sgn * xi[j] + pi;
  }
  if (qq) {
#pragma unroll
    for (int k = 1; k < 16; ++k) cmul(xr[REV[k]], xi[REV[k]], W32C[k], W32S[k]);
  }
  dft16_inv(xr, xi);
  // B3 (write set == B2's read set)
  int base2 = ((t >> 5) << 9) + (t & 31);
  int base3 = ((t >> 1) << 5) + qq;
#pragma unroll
  for (int m = 0; m < 16; ++m) { int p = base3 + (m << 1); p += p >> 5; lbuf[p] = xr[m]; }
  __syncthreads();
#pragma unroll
  for (int j = 0; j < 16; ++j) { int p = base2 + (REV[j] << 5); p += p >> 5; xr[j] = lbuf[p]; }
  __syncthreads();
#pragma unroll
  for (int m = 0; m < 16; ++m) { int p = base3 + (m << 1); p += p >> 5; lbuf[p] = xi[m]; }
  __syncthreads();
#pragma unroll
  for (int j = 0; j < 16; ++j) { int p = base2 + (REV[j] << 5); p += p >> 5; xi[j] = lbuf[p]; }
  // iS2
  {
    float2 w1 = tw[(t & 31) << 4];
    TWCHAIN(xr, xi, w1.x, -w1.y);
  }
  dft16_inv(xr, xi);
  // B4
#pragma unroll
  for (int m = 0; m < 16; ++m) { int p = base2 + (m << 5); p += p >> 5; lbuf[p] = xr[m]; }
  __syncthreads();
#pragma unroll
  for (int j = 0; j < 16; ++j) { int p = t + (REV[j] << 9); p += p >> 5; xr[j] = lbuf[p]; }
  __syncthreads();
#pragma unroll
  for (int m = 0; m < 16; ++m) { int p = base2 + (m << 5); p += p >> 5; lbuf[p] = xi[m]; }
  __syncthreads();
#pragma unroll
  for (int j = 0; j < 16; ++j) { int p = t + (REV[j] << 9); p += p >> 5; xi[j] = lbuf[p]; }
  // iS1
  {
    float2 w1 = tw[t];
    TWCHAIN(xr, xi, w1.x, -w1.y);
  }
  dft16_inv(xr, xi);
}

// ---------------- setup: build normalized k, twiddles, W^T ----------------
__global__ void __launch_bounds__(256) gconv_setup(
    const float* __restrict__ kernels,  // [8][1][256][32]
    const float* __restrict__ W_out,    // [256][256]
    float* __restrict__ k_norm,         // [256][4096]
    float2* __restrict__ tw,            // [512]
    float* __restrict__ Wt)             // [256][256]
{
  int blk = blockIdx.x;
  int tid = threadIdx.x;
  if (blk < 256) {
    int h = blk;
    __shared__ float red[256];
    float val[16];
    float ss = 0.0f;
#pragma unroll
    for (int r = 0; r < 16; ++r) {
      int l = tid + 256 * r;
      int i;
      if (l < 32) i = 0;
      else if (l < 64) i = 1;
      else i = (31 - __clz(l)) - 4;
      int off = (i == 0) ? 0 : (16 << i);
      int s = (i <= 1) ? 1 : (1 << (i - 1));
      float mult = (float)(1 << (7 - i));
      int j = l - off;
      const float* kb = kernels + ((size_t)i * 256 + h) * 32;
      float v;
      if (s == 1) {
        v = kb[j];
      } else {
        float x = ((float)j + 0.5f) / (float)s - 0.5f;
        x = fminf(fmaxf(x, 0.0f), 31.0f);
        float xf = floorf(x);
        int x0 = (int)xf;
        int x1 = min(x0 + 1, 31);
        float w = x - xf;
        v = kb[x0] * (1.0f - w) + kb[x1] * w;
      }
      v *= mult;
      val[r] = v;
      ss += v * v;
    }
    red[tid] = ss;
    __syncthreads();
    for (int o = 128; o > 0; o >>= 1) {
      if (tid < o) red[tid] += red[tid + o];
      __syncthreads();
    }
    float inv = 1.0f / sqrtf(red[0]);
#pragma unroll
    for (int r = 0; r < 16; ++r)
      k_norm[(size_t)h * 4096 + tid + 256 * r] = val[r] * inv;
  } else if (blk < 258) {
    int idx = (blk - 256) * 256 + tid;  // 0..511
    double ang = -6.283185307179586477 * (double)idx / 8192.0;
    tw[idx] = make_float2((float)cos(ang), (float)sin(ang));
  } else {
    int o = (blk - 258) * 256 + tid;    // 0..65535 ; Wt[h][h'] = W_out[h'][h]
    Wt[o] = W_out[(o & 255) * 256 + (o >> 8)];
  }
}

// ---------------- kernel FFT: K_hat (permuted layout), D and 1/N folded ---
__global__ void __launch_bounds__(512, 4) gconv_kfft(
    const float* __restrict__ k_norm,
    const float* __restrict__ Dvec,
    const float2* __restrict__ tw,
    float2* __restrict__ Kst)           // [256][8192], index h*8192 + t*16 + j
{
  __shared__ float lbuf[8448];
  int h = blockIdx.x;
  int t = threadIdx.x;
  float xr[16], xi[16];
  const float* kn = k_norm + ((size_t)h << 12);
#pragma unroll
  for (int m = 0; m < 8; ++m) { xr[m] = kn[t + (m << 9)]; xi[m] = 0.f; }
#pragma unroll
  for (int m = 8; m < 16; ++m) { xr[m] = 0.f; xi[m] = 0.f; }
  fft8192_fwd(xr, xi, lbuf, t, tw);
  float Dh = Dvec[h];
  const float sc = 1.0f / 8192.0f;
  float2* out = Kst + ((size_t)h << 13) + (t << 4);
#pragma unroll
  for (int j = 0; j < 16; ++j)
    out[j] = make_float2((xr[j] + Dh) * sc, xi[j] * sc);
}

// ---------------- main: fwd FFT (b-pair packed), multiply, inv FFT, gelu --
__global__ void __launch_bounds__(512, 4) gconv_main(
    const float* __restrict__ u,
    const float2* __restrict__ tw,
    const float2* __restrict__ Kst,
    unsigned short* __restrict__ g)     // bf16 [16][256][4096]
{
  __shared__ float lbuf[8448];
  int blk = blockIdx.x;
  int h = blk & 255;
  int pb = blk >> 8;                    // 0..7 ; batches pb and pb+8
  int t = threadIdx.x;
  const float* u0 = u + ((size_t)(pb * 256 + h) << 12);
  const float* u1 = u + ((size_t)((pb + 8) * 256 + h) << 12);
  float xr[16], xi[16];
#pragma unroll
  for (int m = 0; m < 8; ++m) { xr[m] = u0[t + (m << 9)]; xi[m] = u1[t + (m << 9)]; }
#pragma unroll
  for (int m = 8; m < 16; ++m) { xr[m] = 0.f; xi[m] = 0.f; }
  fft8192_fwd(xr, xi, lbuf, t, tw);
  const float2* kr = Kst + ((size_t)h << 13) + (t << 4);
#pragma unroll
  for (int j = 0; j < 16; ++j) {
    float2 kv = kr[j];
    cmul(xr[j], xi[j], kv.x, kv.y);
  }
  fft8192_inv(xr, xi, lbuf, t, tw);
  // gelu(exact) + store bf16 (keep first 4096 samples: m = 0..7)
  unsigned short* g0 = g + ((size_t)(pb * 256 + h) << 12) + t;
  unsigned short* g1 = g + ((size_t)((pb + 8) * 256 + h) << 12) + t;
#pragma unroll
  for (int m = 0; m < 8; ++m) {
    float y0 = xr[m], y1 = xi[m];
    y0 = 0.5f * y0 * (1.f + erff(y0 * 0.70710678118654752f));
    y1 = 0.5f * y1 * (1.f + erff(y1 * 0.70710678118654752f));
    g0[m << 9] = f2bf(y0);
    g1[m << 9] = f2bf(y1);
  }
}

// ---------------- output projection: out = W @ g + b ----------------------
__global__ void __launch_bounds__(256) gconv_out(
    const unsigned short* __restrict__ g,   // bf16 [16][256][4096]
    const float* __restrict__ Wt,           // [k=256][m=256]
    const float* __restrict__ b_out,        // [256]
    float* __restrict__ out)                // [16][256][4096]
{
  __shared__ float As[16][128];
  __shared__ unsigned short Bs[16][128];
  int nt = blockIdx.x;
  int mt = blockIdx.y;
  int b  = blockIdx.z;
  int l0 = nt * 128, m0 = mt * 128;
  int tid = threadIdx.x;
  int tx = tid & 15, ty = tid >> 4;
  float acc[8][8];
#pragma unroll
  for (int ii = 0; ii < 8; ++ii)
#pragma unroll
    for (int jj = 0; jj < 8; ++jj) acc[ii][jj] = 0.0f;

  for (int kc = 0; kc < 16; ++kc) {
#pragma unroll
    for (int q = 0; q < 2; ++q) {
      int qq = tid + q * 256;
      int row = qq >> 5, c4 = qq & 31;
      ((float4*)&As[row][0])[c4] =
          *(const float4*)(Wt + (size_t)(kc * 16 + row) * 256 + m0 + c4 * 4);
    }
    {
      int row = tid >> 4, c8 = tid & 15;
      ((uint4*)&Bs[row][0])[c8] =
          *(const uint4*)(g + ((size_t)(b * 256 + kc * 16 + row) << 12) + l0 + c8 * 8);
    }
    __syncthreads();
#pragma unroll
    for (int k = 0; k < 16; ++k) {
      float a[8];
      ((float4*)a)[0] = *(const float4*)&As[k][ty * 8];
      ((float4*)a)[1] = *(const float4*)&As[k][ty * 8 + 4];
      uint4 bp = *(const uint4*)&Bs[k][tx * 8];
      float bb[8];
      bb[0] = __uint_as_float(bp.x << 16);
      bb[1] = __uint_as_float(bp.x & 0xFFFF0000u);
      bb[2] = __uint_as_float(bp.y << 16);
      bb[3] = __uint_as_float(bp.y & 0xFFFF0000u);
      bb[4] = __uint_as_float(bp.z << 16);
      bb[5] = __uint_as_float(bp.z & 0xFFFF0000u);
      bb[6] = __uint_as_float(bp.w << 16);
      bb[7] = __uint_as_float(bp.w & 0xFFFF0000u);
#pragma unroll
      for (int ii = 0; ii < 8; ++ii)
#pragma unroll
        for (int jj = 0; jj < 8; ++jj) acc[ii][jj] += a[ii] * bb[jj];
    }
    __syncthreads();
  }
#pragma unroll
  for (int ii = 0; ii < 8; ++ii) {
    int m = m0 + ty * 8 + ii;
    float bias = b_out[m];
    float* op = out + ((size_t)(b * 256 + m) << 12) + l0 + tx * 8;
    float4 v0 = make_float4(acc[ii][0] + bias, acc[ii][1] + bias,
                            acc[ii][2] + bias, acc[ii][3] + bias);
    float4 v1 = make_float4(acc[ii][4] + bias, acc[ii][5] + bias,
                            acc[ii][6] + bias, acc[ii][7] + bias);
    ((float4*)op)[0] = v0;
    ((float4*)op)[1] = v1;
  }
}

extern "C" void kernel_launch(void* const* d_in, const int* in_sizes, int n_in,
                              void* d_out, int out_size, void* d_ws, size_t ws_size,
                              hipStream_t stream) {
  (void)in_sizes; (void)n_in; (void)out_size; (void)ws_size;
  const float* u       = (const float*)d_in[0];
  const float* kernels = (const float*)d_in[1];
  const float* Dvec    = (const float*)d_in[2];
  const float* W_out   = (const float*)d_in[3];
  const float* b_out   = (const float*)d_in[4];
  float* out = (float*)d_out;
  char* ws = (char*)d_ws;

  float*  k_norm = (float*)(ws);
  float2* tw     = (float2*)(ws + (4u << 20));
  float*  Wt     = (float*)(ws + (4u << 20) + (128u << 10));
  float2* Kst    = (float2*)(ws + (8u << 20));
  unsigned short* g = (unsigned short*)(ws + (24u << 20));

  gconv_setup<<<514, 256, 0, stream>>>(kernels, W_out, k_norm, tw, Wt);
  gconv_kfft<<<256, 512, 0, stream>>>(k_norm, Dvec, tw, Kst);
  gconv_main<<<2048, 512, 0, stream>>>(u, tw, Kst, g);
  dim3 gd(32, 2, 16);
  gconv_out<<<gd, 256, 0, stream>>>(g, Wt, b_out, out);
}

// Round 8
// 123.930 us; speedup vs baseline: 3.8290x; 1.9584x over previous
//
#include <hip/hip_runtime.h>

// ws layout (needs >= 56 MB):
//   [0x0000000, 0x0400000) k_norm f32 [256][4096]            (4 MB)
//   [0x0400000, 0x0401000) tw float2[512]                    (4 KB)
//   [0x0420000, 0x0440000) Wbf bf16 [256 m][256 h]           (128 KB)
//   [0x0800000, 0x1800000) Kst float2 [256][8192]            (16 MB)
//   [0x1800000, 0x3800000) g bf16 [16][256][4096]            (32 MB)

#define C1f 0.92387953251128674f
#define S1f 0.38268343236508977f
#define C2f 0.70710678118654752f

typedef __attribute__((ext_vector_type(8))) short bf16x8;
typedef __attribute__((ext_vector_type(4))) float f32x4;

static __device__ __forceinline__ unsigned short f2bf(float f) {
  unsigned u = __float_as_uint(f);
  u += 0x7FFFu + ((u >> 16) & 1u);
  return (unsigned short)(u >> 16);
}

static __device__ __forceinline__ void cmul(float& ar, float& ai, float br, float bi) {
  float t = ar * br - ai * bi;
  ai = ar * bi + ai * br;
  ar = t;
}

// w32^k, k=0..15 (for S3 twiddles; forward uses -sin, inverse +sin)
__device__ __constant__ float W32C[16] = {
  1.f, 0.98078528040323044913f, 0.92387953251128675613f, 0.83146961230254523708f,
  0.70710678118654752440f, 0.55557023301960222474f, 0.38268343236508977173f,
  0.19509032201612826785f, 0.f, -0.19509032201612826785f, -0.38268343236508977173f,
  -0.55557023301960222474f, -0.70710678118654752440f, -0.83146961230254523708f,
  -0.92387953251128675613f, -0.98078528040323044913f};
__device__ __constant__ float W32S[16] = {
  0.f, 0.19509032201612826785f, 0.38268343236508977173f, 0.55557023301960222474f,
  0.70710678118654752440f, 0.83146961230254523708f, 0.92387953251128675613f,
  0.98078528040323044913f, 1.f, 0.98078528040323044913f, 0.92387953251128675613f,
  0.83146961230254523708f, 0.70710678118654752440f, 0.55557023301960222474f,
  0.38268343236508977173f, 0.19509032201612826785f};

// forward 16-pt DFT, DIF radix-2, in-place; output slot p holds X[rev4(p)]
static __device__ __forceinline__ void dft16_fwd(float* xr, float* xi) {
  const float wr[8] = {1.f, C1f, C2f, S1f, 0.f, -S1f, -C2f, -C1f};
  const float wi[8] = {0.f, -S1f, -C2f, -C1f, -1.f, -C1f, -C2f, -S1f};
#pragma unroll
  for (int j = 0; j < 8; ++j) {
    float ar = xr[j], ai = xi[j], br = xr[j + 8], bi = xi[j + 8];
    xr[j] = ar + br; xi[j] = ai + bi;
    float dr = ar - br, di = ai - bi;
    xr[j + 8] = dr * wr[j] - di * wi[j];
    xi[j + 8] = dr * wi[j] + di * wr[j];
  }
#pragma unroll
  for (int h = 0; h < 2; ++h) {
#pragma unroll
    for (int j = 0; j < 4; ++j) {
      int i0 = h * 8 + j, i1 = i0 + 4;
      float ar = xr[i0], ai = xi[i0], br = xr[i1], bi = xi[i1];
      xr[i0] = ar + br; xi[i0] = ai + bi;
      float dr = ar - br, di = ai - bi;
      xr[i1] = dr * wr[2 * j] - di * wi[2 * j];
      xi[i1] = dr * wi[2 * j] + di * wr[2 * j];
    }
  }
#pragma unroll
  for (int h = 0; h < 4; ++h) {
    int base = h * 4;
    {
      int i0 = base, i1 = base + 2;
      float ar = xr[i0], ai = xi[i0], br = xr[i1], bi = xi[i1];
      xr[i0] = ar + br; xi[i0] = ai + bi;
      xr[i1] = ar - br; xi[i1] = ai - bi;
    }
    {
      int i0 = base + 1, i1 = base + 3;
      float ar = xr[i0], ai = xi[i0], br = xr[i1], bi = xi[i1];
      xr[i0] = ar + br; xi[i0] = ai + bi;
      float dr = ar - br, di = ai - bi;
      xr[i1] = di; xi[i1] = -dr;
    }
  }
#pragma unroll
  for (int h = 0; h < 8; ++h) {
    int i0 = h * 2, i1 = i0 + 1;
    float ar = xr[i0], ai = xi[i0], br = xr[i1], bi = xi[i1];
    xr[i0] = ar + br; xi[i0] = ai + bi;
    xr[i1] = ar - br; xi[i1] = ai - bi;
  }
}

// inverse 16-pt DFT (conjugate mirror, no scaling); input slot p = X[rev4(p)]
static __device__ __forceinline__ void dft16_inv(float* xr, float* xi) {
  const float wr[8] = {1.f, C1f, C2f, S1f, 0.f, -S1f, -C2f, -C1f};
  const float wi[8] = {0.f, S1f, C2f, C1f, 1.f, C1f, C2f, S1f};
#pragma unroll
  for (int h = 0; h < 8; ++h) {
    int i0 = h * 2, i1 = i0 + 1;
    float ar = xr[i0], ai = xi[i0], br = xr[i1], bi = xi[i1];
    xr[i0] = ar + br; xi[i0] = ai + bi;
    xr[i1] = ar - br; xi[i1] = ai - bi;
  }
#pragma unroll
  for (int h = 0; h < 4; ++h) {
    int base = h * 4;
    {
      int i0 = base, i1 = base + 2;
      float ar = xr[i0], ai = xi[i0], tr = xr[i1], ti = xi[i1];
      xr[i0] = ar + tr; xi[i0] = ai + ti;
      xr[i1] = ar - tr; xi[i1] = ai - ti;
    }
    {
      int i0 = base + 1, i1 = base + 3;
      float ar = xr[i0], ai = xi[i0], br = xr[i1], bi = xi[i1];
      float tr = -bi, ti = br;
      xr[i0] = ar + tr; xi[i0] = ai + ti;
      xr[i1] = ar - tr; xi[i1] = ai - ti;
    }
  }
#pragma unroll
  for (int h = 0; h < 2; ++h) {
#pragma unroll
    for (int j = 0; j < 4; ++j) {
      int i0 = h * 8 + j, i1 = i0 + 4;
      float br = xr[i1], bi = xi[i1];
      float tr = br * wr[2 * j] - bi * wi[2 * j];
      float ti = br * wi[2 * j] + bi * wr[2 * j];
      float ar = xr[i0], ai = xi[i0];
      xr[i0] = ar + tr; xi[i0] = ai + ti;
      xr[i1] = ar - tr; xi[i1] = ai - ti;
    }
  }
#pragma unroll
  for (int j = 0; j < 8; ++j) {
    int i0 = j, i1 = j + 8;
    float br = xr[i1], bi = xi[i1];
    float tr = br * wr[j] - bi * wi[j];
    float ti = br * wi[j] + bi * wr[j];
    float ar = xr[i0], ai = xi[i0];
    xr[i0] = ar + tr; xi[i0] = ai + ti;
    xr[i1] = ar - tr; xi[i1] = ai - ti;
  }
}

#define REV_INIT constexpr int REV[16] = {0, 8, 4, 12, 2, 10, 6, 14, 1, 9, 5, 13, 3, 11, 7, 15}

// apply slot-j twiddle w^(REV[j]) by power chain from base (cr,ci); REV is an involution
#define TWCHAIN(XR, XI, CR, CI)                         \
  {                                                     \
    float pr_ = (CR), pi_ = (CI);                       \
    cmul(XR[8], XI[8], pr_, pi_);                       \
    _Pragma("unroll") for (int k = 2; k < 16; ++k) {    \
      cmul(pr_, pi_, (CR), (CI));                       \
      cmul(XR[REV[k]], XI[REV[k]], pr_, pi_);           \
    }                                                   \
  }

// 8192-pt forward FFT across 512 threads (see round-5 notes for layout math)
static __device__ __forceinline__ void fft8192_fwd(float* xr, float* xi, float* lbuf,
                                                   int t, const float2* __restrict__ tw) {
  REV_INIT;
  dft16_fwd(xr, xi);
  {
    float2 w1 = tw[t];
    TWCHAIN(xr, xi, w1.x, w1.y);
  }
  int base2 = ((t >> 5) << 9) + (t & 31);
#pragma unroll
  for (int j = 0; j < 16; ++j) { int p = t + (REV[j] << 9); p += p >> 5; lbuf[p] = xr[j]; }
  __syncthreads();
#pragma unroll
  for (int m = 0; m < 16; ++m) { int p = base2 + (m << 5); p += p >> 5; xr[m] = lbuf[p]; }
  __syncthreads();
#pragma unroll
  for (int j = 0; j < 16; ++j) { int p = t + (REV[j] << 9); p += p >> 5; lbuf[p] = xi[j]; }
  __syncthreads();
#pragma unroll
  for (int m = 0; m < 16; ++m) { int p = base2 + (m << 5); p += p >> 5; xi[m] = lbuf[p]; }
  dft16_fwd(xr, xi);
  {
    float2 w1 = tw[(t & 31) << 4];
    TWCHAIN(xr, xi, w1.x, w1.y);
  }
  int qq = t & 1;
  int base3 = ((t >> 1) << 5) + qq;
#pragma unroll
  for (int j = 0; j < 16; ++j) { int p = base2 + (REV[j] << 5); p += p >> 5; lbuf[p] = xr[j]; }
  __syncthreads();
#pragma unroll
  for (int m = 0; m < 16; ++m) { int p = base3 + (m << 1); p += p >> 5; xr[m] = lbuf[p]; }
  __syncthreads();
#pragma unroll
  for (int j = 0; j < 16; ++j) { int p = base2 + (REV[j] << 5); p += p >> 5; lbuf[p] = xi[j]; }
  __syncthreads();
#pragma unroll
  for (int m = 0; m < 16; ++m) { int p = base3 + (m << 1); p += p >> 5; xi[m] = lbuf[p]; }
  dft16_fwd(xr, xi);
  if (qq) {
#pragma unroll
    for (int k = 1; k < 16; ++k) cmul(xr[REV[k]], xi[REV[k]], W32C[k], -W32S[k]);
  }
  float sgn = qq ? -1.f : 1.f;
#pragma unroll
  for (int j = 0; j < 16; ++j) {
    float pr = __shfl_xor(xr[j], 1);
    float pi = __shfl_xor(xi[j], 1);
    xr[j] = sgn * xr[j] + pr;
    xi[j] = sgn * xi[j] + pi;
  }
}

// exact inverse (conjugate twiddles, mirrored); scale 8192 folded into Kst.
static __device__ __forceinline__ void fft8192_inv(float* xr, float* xi, float* lbuf,
                                                   int t, const float2* __restrict__ tw) {
  REV_INIT;
  int qq = t & 1;
  float sgn = qq ? -1.f : 1.f;
#pragma unroll
  for (int j = 0; j < 16; ++j) {
    float pr = __shfl_xor(xr[j], 1);
    float pi = __shfl_xor(xi[j], 1);
    xr[j] = sgn * xr[j] + pr;
    xi[j] = sgn * xi[j] + pi;
  }
  if (qq) {
#pragma unroll
    for (int k = 1; k < 16; ++k) cmul(xr[REV[k]], xi[REV[k]], W32C[k], W32S[k]);
  }
  dft16_inv(xr, xi);
  int base2 = ((t >> 5) << 9) + (t & 31);
  int base3 = ((t >> 1) << 5) + qq;
#pragma unroll
  for (int m = 0; m < 16; ++m) { int p = base3 + (m << 1); p += p >> 5; lbuf[p] = xr[m]; }
  __syncthreads();
#pragma unroll
  for (int j = 0; j < 16; ++j) { int p = base2 + (REV[j] << 5); p += p >> 5; xr[j] = lbuf[p]; }
  __syncthreads();
#pragma unroll
  for (int m = 0; m < 16; ++m) { int p = base3 + (m << 1); p += p >> 5; lbuf[p] = xi[m]; }
  __syncthreads();
#pragma unroll
  for (int j = 0; j < 16; ++j) { int p = base2 + (REV[j] << 5); p += p >> 5; xi[j] = lbuf[p]; }
  {
    float2 w1 = tw[(t & 31) << 4];
    TWCHAIN(xr, xi, w1.x, -w1.y);
  }
  dft16_inv(xr, xi);
#pragma unroll
  for (int m = 0; m < 16; ++m) { int p = base2 + (m << 5); p += p >> 5; lbuf[p] = xr[m]; }
  __syncthreads();
#pragma unroll
  for (int j = 0; j < 16; ++j) { int p = t + (REV[j] << 9); p += p >> 5; xr[j] = lbuf[p]; }
  __syncthreads();
#pragma unroll
  for (int m = 0; m < 16; ++m) { int p = base2 + (m << 5); p += p >> 5; lbuf[p] = xi[m]; }
  __syncthreads();
#pragma unroll
  for (int j = 0; j < 16; ++j) { int p = t + (REV[j] << 9); p += p >> 5; xi[j] = lbuf[p]; }
  {
    float2 w1 = tw[t];
    TWCHAIN(xr, xi, w1.x, -w1.y);
  }
  dft16_inv(xr, xi);
}

// ---------------- setup: build normalized k, twiddles, Wbf ----------------
__global__ void __launch_bounds__(256) gconv_setup(
    const float* __restrict__ kernels,  // [8][1][256][32]
    const float* __restrict__ W_out,    // [256][256]
    float* __restrict__ k_norm,         // [256][4096]
    float2* __restrict__ tw,            // [512]
    unsigned short* __restrict__ Wbf)   // bf16 [256 m][256 h]
{
  int blk = blockIdx.x;
  int tid = threadIdx.x;
  if (blk < 256) {
    int h = blk;
    __shared__ float red[256];
    float val[16];
    float ss = 0.0f;
#pragma unroll
    for (int r = 0; r < 16; ++r) {
      int l = tid + 256 * r;
      int i;
      if (l < 32) i = 0;
      else if (l < 64) i = 1;
      else i = (31 - __clz(l)) - 4;
      int off = (i == 0) ? 0 : (16 << i);
      int s = (i <= 1) ? 1 : (1 << (i - 1));
      float mult = (float)(1 << (7 - i));
      int j = l - off;
      const float* kb = kernels + ((size_t)i * 256 + h) * 32;
      float v;
      if (s == 1) {
        v = kb[j];
      } else {
        float x = ((float)j + 0.5f) / (float)s - 0.5f;
        x = fminf(fmaxf(x, 0.0f), 31.0f);
        float xf = floorf(x);
        int x0 = (int)xf;
        int x1 = min(x0 + 1, 31);
        float w = x - xf;
        v = kb[x0] * (1.0f - w) + kb[x1] * w;
      }
      v *= mult;
      val[r] = v;
      ss += v * v;
    }
    red[tid] = ss;
    __syncthreads();
    for (int o = 128; o > 0; o >>= 1) {
      if (tid < o) red[tid] += red[tid + o];
      __syncthreads();
    }
    float inv = 1.0f / sqrtf(red[0]);
#pragma unroll
    for (int r = 0; r < 16; ++r)
      k_norm[(size_t)h * 4096 + tid + 256 * r] = val[r] * inv;
  } else if (blk < 258) {
    int idx = (blk - 256) * 256 + tid;  // 0..511
    double ang = -6.283185307179586477 * (double)idx / 8192.0;
    tw[idx] = make_float2((float)cos(ang), (float)sin(ang));
  } else {
    int o = (blk - 258) * 256 + tid;    // 0..65535 ; same [m][h] layout as W_out
    Wbf[o] = f2bf(W_out[o]);
  }
}

// ---------------- kernel FFT: K_hat (permuted layout), D and 1/N folded ---
__global__ void __launch_bounds__(512, 4) gconv_kfft(
    const float* __restrict__ k_norm,
    const float* __restrict__ Dvec,
    const float2* __restrict__ tw,
    float2* __restrict__ Kst)           // [256][8192], index h*8192 + t*16 + j
{
  __shared__ float lbuf[8448];
  int h = blockIdx.x;
  int t = threadIdx.x;
  float xr[16], xi[16];
  const float* kn = k_norm + ((size_t)h << 12);
#pragma unroll
  for (int m = 0; m < 8; ++m) { xr[m] = kn[t + (m << 9)]; xi[m] = 0.f; }
#pragma unroll
  for (int m = 8; m < 16; ++m) { xr[m] = 0.f; xi[m] = 0.f; }
  fft8192_fwd(xr, xi, lbuf, t, tw);
  float Dh = Dvec[h];
  const float sc = 1.0f / 8192.0f;
  float2* out = Kst + ((size_t)h << 13) + (t << 4);
#pragma unroll
  for (int j = 0; j < 16; ++j)
    out[j] = make_float2((xr[j] + Dh) * sc, xi[j] * sc);
}

// ---------------- main: fwd FFT (b-pair packed), multiply, inv FFT, gelu --
__global__ void __launch_bounds__(512, 4) gconv_main(
    const float* __restrict__ u,
    const float2* __restrict__ tw,
    const float2* __restrict__ Kst,
    unsigned short* __restrict__ g)     // bf16 [16][256][4096]
{
  __shared__ float lbuf[8448];
  int blk = blockIdx.x;
  int h = blk & 255;
  int pb = blk >> 8;                    // 0..7 ; batches pb and pb+8
  int t = threadIdx.x;
  const float* u0 = u + ((size_t)(pb * 256 + h) << 12);
  const float* u1 = u + ((size_t)((pb + 8) * 256 + h) << 12);
  float xr[16], xi[16];
#pragma unroll
  for (int m = 0; m < 8; ++m) { xr[m] = u0[t + (m << 9)]; xi[m] = u1[t + (m << 9)]; }
#pragma unroll
  for (int m = 8; m < 16; ++m) { xr[m] = 0.f; xi[m] = 0.f; }
  fft8192_fwd(xr, xi, lbuf, t, tw);
  const float2* kr = Kst + ((size_t)h << 13) + (t << 4);
#pragma unroll
  for (int j = 0; j < 16; ++j) {
    float2 kv = kr[j];
    cmul(xr[j], xi[j], kv.x, kv.y);
  }
  fft8192_inv(xr, xi, lbuf, t, tw);
  unsigned short* g0 = g + ((size_t)(pb * 256 + h) << 12) + t;
  unsigned short* g1 = g + ((size_t)((pb + 8) * 256 + h) << 12) + t;
#pragma unroll
  for (int m = 0; m < 8; ++m) {
    float y0 = xr[m], y1 = xi[m];
    y0 = 0.5f * y0 * (1.f + erff(y0 * 0.70710678118654752f));
    y1 = 0.5f * y1 * (1.f + erff(y1 * 0.70710678118654752f));
    g0[m << 9] = f2bf(y0);
    g1[m << 9] = f2bf(y1);
  }
}

// -------- output projection (MFMA): out[b][m][l] = sum_h W[m][h] g[b][h][l] + b[m]
__global__ void __launch_bounds__(256) gconv_out(
    const unsigned short* __restrict__ g,   // bf16 [16][256][4096]
    const unsigned short* __restrict__ Wbf, // bf16 [256 m][256 h]
    const float* __restrict__ b_out,        // [256]
    float* __restrict__ out)                // [16][256][4096]
{
  __shared__ unsigned short As[128][40];    // [m][k], 80B rows (16B aligned)
  __shared__ unsigned short Bs[32][132];    // [k][l], 264B rows (bank-staggered)
  int l0 = blockIdx.x * 128;
  int m0 = blockIdx.y * 128;
  int b  = blockIdx.z;
  int tid = threadIdx.x;
  int lane = tid & 63, wid = tid >> 6;
  int wm = (wid >> 1) * 64, wl = (wid & 1) * 64;  // wave quadrant
  int lhi = lane >> 4, llo = lane & 15;
  f32x4 acc[4][4];
#pragma unroll
  for (int a = 0; a < 4; ++a)
#pragma unroll
    for (int c = 0; c < 4; ++c) acc[a][c] = (f32x4){0.f, 0.f, 0.f, 0.f};

  for (int ks = 0; ks < 8; ++ks) {
    int k0 = ks * 32;
#pragma unroll
    for (int i = 0; i < 2; ++i) {
      int idx = tid + i * 256;
      int m = idx >> 2, c = idx & 3;           // A: 128 rows x 4 chunks of 8
      *(uint4*)&As[m][c * 8] =
          *(const uint4*)(Wbf + ((size_t)(m0 + m) << 8) + k0 + c * 8);
      int k = idx >> 4, cc = idx & 15;         // B: 32 rows x 16 chunks of 8
      const unsigned short* gp =
          g + ((size_t)(b * 256 + k0 + k) << 12) + l0 + cc * 8;
      ((uint2*)&Bs[k][cc * 8])[0] = ((const uint2*)gp)[0];
      ((uint2*)&Bs[k][cc * 8])[1] = ((const uint2*)gp)[1];
    }
    __syncthreads();
    int kk = lhi * 8;
    bf16x8 af[4], bfr[4];
#pragma unroll
    for (int f = 0; f < 4; ++f)
      af[f] = *(bf16x8*)&As[wm + f * 16 + llo][kk];
#pragma unroll
    for (int f = 0; f < 4; ++f) {
      bf16x8 v;
#pragma unroll
      for (int j = 0; j < 8; ++j)
        v[j] = (short)Bs[kk + j][wl + f * 16 + llo];
      bfr[f] = v;
    }
#pragma unroll
    for (int fm = 0; fm < 4; ++fm)
#pragma unroll
      for (int fl = 0; fl < 4; ++fl)
        acc[fm][fl] = __builtin_amdgcn_mfma_f32_16x16x32_bf16(
            af[fm], bfr[fl], acc[fm][fl], 0, 0, 0);
    __syncthreads();
  }
#pragma unroll
  for (int fm = 0; fm < 4; ++fm) {
#pragma unroll
    for (int r = 0; r < 4; ++r) {
      int m = m0 + wm + fm * 16 + lhi * 4 + r;
      float bias = b_out[m];
      float* op = out + ((size_t)(b * 256 + m) << 12) + l0 + wl + llo;
#pragma unroll
      for (int fl = 0; fl < 4; ++fl)
        op[fl * 16] = acc[fm][fl][r] + bias;
    }
  }
}

extern "C" void kernel_launch(void* const* d_in, const int* in_sizes, int n_in,
                              void* d_out, int out_size, void* d_ws, size_t ws_size,
                              hipStream_t stream) {
  (void)in_sizes; (void)n_in; (void)out_size; (void)ws_size;
  const float* u       = (const float*)d_in[0];
  const float* kernels = (const float*)d_in[1];
  const float* Dvec    = (const float*)d_in[2];
  const float* W_out   = (const float*)d_in[3];
  const float* b_out   = (const float*)d_in[4];
  float* out = (float*)d_out;
  char* ws = (char*)d_ws;

  float*  k_norm = (float*)(ws);
  float2* tw     = (float2*)(ws + (4u << 20));
  unsigned short* Wbf = (unsigned short*)(ws + (4u << 20) + (128u << 10));
  float2* Kst    = (float2*)(ws + (8u << 20));
  unsigned short* g = (unsigned short*)(ws + (24u << 20));

  gconv_setup<<<514, 256, 0, stream>>>(kernels, W_out, k_norm, tw, Wbf);
  gconv_kfft<<<256, 512, 0, stream>>>(k_norm, Dvec, tw, Kst);
  gconv_main<<<2048, 512, 0, stream>>>(u, tw, Kst, g);
  dim3 gd(32, 2, 16);
  gconv_out<<<gd, 256, 0, stream>>>(g, Wbf, b_out, out);
}

// Round 9
// 112.049 us; speedup vs baseline: 4.2350x; 1.1060x over previous
//
#include <hip/hip_runtime.h>

// ws layout (needs >= 56 MB):
//   [0x0000000, 0x0400000) k_norm f32 [256][4096]            (4 MB)
//   [0x0400000, 0x0401000) tw float2[512]                    (4 KB)
//   [0x0420000, 0x0440000) Wbf bf16 [256 m][256 h]           (128 KB)
//   [0x0800000, 0x1800000) Kst float2 [256][8192]            (16 MB)
//   [0x1800000, 0x3800000) g bf16 [16][256][4096]            (32 MB)

#define C1f 0.92387953251128674f
#define S1f 0.38268343236508977f
#define C2f 0.70710678118654752f

typedef __attribute__((ext_vector_type(8))) short bf16x8;
typedef __attribute__((ext_vector_type(4))) float f32x4;

static __device__ __forceinline__ unsigned short f2bf(float f) {
  unsigned u = __float_as_uint(f);
  u += 0x7FFFu + ((u >> 16) & 1u);
  return (unsigned short)(u >> 16);
}

static __device__ __forceinline__ void cmul(float& ar, float& ai, float br, float bi) {
  float t = ar * br - ai * bi;
  ai = ar * bi + ai * br;
  ar = t;
}

// tanh-form GeLU (max |err| vs exact ~3e-3, absorbed by bf16-g + threshold)
static __device__ __forceinline__ float gelu_t(float x) {
  float x2 = x * x;
  float t = x * __builtin_fmaf(0.044715f, x2, 1.f);   // x + 0.044715 x^3
  float e = __expf(-1.5957691216f * t);               // exp(-2a t)
  return x / (1.f + e);
}

// w32^k, k=0..15 (for S3 twiddles; forward uses -sin, inverse +sin)
__device__ __constant__ float W32C[16] = {
  1.f, 0.98078528040323044913f, 0.92387953251128675613f, 0.83146961230254523708f,
  0.70710678118654752440f, 0.55557023301960222474f, 0.38268343236508977173f,
  0.19509032201612826785f, 0.f, -0.19509032201612826785f, -0.38268343236508977173f,
  -0.55557023301960222474f, -0.70710678118654752440f, -0.83146961230254523708f,
  -0.92387953251128675613f, -0.98078528040323044913f};
__device__ __constant__ float W32S[16] = {
  0.f, 0.19509032201612826785f, 0.38268343236508977173f, 0.55557023301960222474f,
  0.70710678118654752440f, 0.83146961230254523708f, 0.92387953251128675613f,
  0.98078528040323044913f, 1.f, 0.98078528040323044913f, 0.92387953251128675613f,
  0.83146961230254523708f, 0.70710678118654752440f, 0.55557023301960222474f,
  0.38268343236508977173f, 0.19509032201612826785f};

// forward 16-pt DFT, DIF radix-2, in-place; output slot p holds X[rev4(p)]
static __device__ __forceinline__ void dft16_fwd(float* xr, float* xi) {
  const float wr[8] = {1.f, C1f, C2f, S1f, 0.f, -S1f, -C2f, -C1f};
  const float wi[8] = {0.f, -S1f, -C2f, -C1f, -1.f, -C1f, -C2f, -S1f};
#pragma unroll
  for (int j = 0; j < 8; ++j) {
    float ar = xr[j], ai = xi[j], br = xr[j + 8], bi = xi[j + 8];
    xr[j] = ar + br; xi[j] = ai + bi;
    float dr = ar - br, di = ai - bi;
    xr[j + 8] = dr * wr[j] - di * wi[j];
    xi[j + 8] = dr * wi[j] + di * wr[j];
  }
#pragma unroll
  for (int h = 0; h < 2; ++h) {
#pragma unroll
    for (int j = 0; j < 4; ++j) {
      int i0 = h * 8 + j, i1 = i0 + 4;
      float ar = xr[i0], ai = xi[i0], br = xr[i1], bi = xi[i1];
      xr[i0] = ar + br; xi[i0] = ai + bi;
      float dr = ar - br, di = ai - bi;
      xr[i1] = dr * wr[2 * j] - di * wi[2 * j];
      xi[i1] = dr * wi[2 * j] + di * wr[2 * j];
    }
  }
#pragma unroll
  for (int h = 0; h < 4; ++h) {
    int base = h * 4;
    {
      int i0 = base, i1 = base + 2;
      float ar = xr[i0], ai = xi[i0], br = xr[i1], bi = xi[i1];
      xr[i0] = ar + br; xi[i0] = ai + bi;
      xr[i1] = ar - br; xi[i1] = ai - bi;
    }
    {
      int i0 = base + 1, i1 = base + 3;
      float ar = xr[i0], ai = xi[i0], br = xr[i1], bi = xi[i1];
      xr[i0] = ar + br; xi[i0] = ai + bi;
      float dr = ar - br, di = ai - bi;
      xr[i1] = di; xi[i1] = -dr;
    }
  }
#pragma unroll
  for (int h = 0; h < 8; ++h) {
    int i0 = h * 2, i1 = i0 + 1;
    float ar = xr[i0], ai = xi[i0], br = xr[i1], bi = xi[i1];
    xr[i0] = ar + br; xi[i0] = ai + bi;
    xr[i1] = ar - br; xi[i1] = ai - bi;
  }
}

// inverse 16-pt DFT (conjugate mirror, no scaling); input slot p = X[rev4(p)].
// HALF=true computes only natural-order outputs 0..7 (upper half dropped).
template <bool HALF>
static __device__ __forceinline__ void dft16_inv_t(float* xr, float* xi) {
  const float wr[8] = {1.f, C1f, C2f, S1f, 0.f, -S1f, -C2f, -C1f};
  const float wi[8] = {0.f, S1f, C2f, C1f, 1.f, C1f, C2f, S1f};
#pragma unroll
  for (int h = 0; h < 8; ++h) {
    int i0 = h * 2, i1 = i0 + 1;
    float ar = xr[i0], ai = xi[i0], br = xr[i1], bi = xi[i1];
    xr[i0] = ar + br; xi[i0] = ai + bi;
    xr[i1] = ar - br; xi[i1] = ai - bi;
  }
#pragma unroll
  for (int h = 0; h < 4; ++h) {
    int base = h * 4;
    {
      int i0 = base, i1 = base + 2;
      float ar = xr[i0], ai = xi[i0], tr = xr[i1], ti = xi[i1];
      xr[i0] = ar + tr; xi[i0] = ai + ti;
      xr[i1] = ar - tr; xi[i1] = ai - ti;
    }
    {
      int i0 = base + 1, i1 = base + 3;
      float ar = xr[i0], ai = xi[i0], br = xr[i1], bi = xi[i1];
      float tr = -bi, ti = br;
      xr[i0] = ar + tr; xi[i0] = ai + ti;
      xr[i1] = ar - tr; xi[i1] = ai - ti;
    }
  }
#pragma unroll
  for (int h = 0; h < 2; ++h) {
#pragma unroll
    for (int j = 0; j < 4; ++j) {
      int i0 = h * 8 + j, i1 = i0 + 4;
      float br = xr[i1], bi = xi[i1];
      float tr = br * wr[2 * j] - bi * wi[2 * j];
      float ti = br * wi[2 * j] + bi * wr[2 * j];
      float ar = xr[i0], ai = xi[i0];
      xr[i0] = ar + tr; xi[i0] = ai + ti;
      xr[i1] = ar - tr; xi[i1] = ai - ti;
    }
  }
#pragma unroll
  for (int j = 0; j < 8; ++j) {
    int i0 = j, i1 = j + 8;
    float br = xr[i1], bi = xi[i1];
    float tr = br * wr[j] - bi * wi[j];
    float ti = br * wi[j] + bi * wr[j];
    float ar = xr[i0], ai = xi[i0];
    xr[i0] = ar + tr; xi[i0] = ai + ti;
    if (!HALF) { xr[i1] = ar - tr; xi[i1] = ai - ti; }
  }
}

#define REV_INIT constexpr int REV[16] = {0, 8, 4, 12, 2, 10, 6, 14, 1, 9, 5, 13, 3, 11, 7, 15}

// apply slot-j twiddle w^(REV[j]) by power chain from base (cr,ci); REV is an involution
#define TWCHAIN(XR, XI, CR, CI)                         \
  {                                                     \
    float pr_ = (CR), pi_ = (CI);                       \
    cmul(XR[8], XI[8], pr_, pi_);                       \
    _Pragma("unroll") for (int k = 2; k < 16; ++k) {    \
      cmul(pr_, pi_, (CR), (CI));                       \
      cmul(XR[REV[k]], XI[REV[k]], pr_, pi_);           \
    }                                                   \
  }

// Padded-address bases (pad p+(p>>5) algebraically folded so every LDS access
// is base + compile-time-const; verified carry-free vs the round-6 addressing):
//   B1 scatter: bs1 + 528*REV[j]   bs1 = t + (t>>5)
//   B1 gather : bg1 + 33*m         bg1 = ((t>>5)<<9) + (t&31) + ((t>>5)<<4)
//   B2 scatter: bg1 + 33*REV[j]
//   B2 gather : bg2 + 2*m          bg2 = 33*(t>>1) + (t&1)
// (inverse boundaries reuse the same sets mirrored)

// 8192-pt forward FFT across 512 threads; thread t enters with reg slot m
// holding x[t + 512 m] (natural); exits with slot j holding spectral value at
// permuted position P(t,j) = (t>>1)*32 + (t&1) + 2*rev4(j).
static __device__ __forceinline__ void fft8192_fwd(float* xr, float* xi, float* lbuf,
                                                   int t, const float2* __restrict__ tw) {
  REV_INIT;
  int bs1 = t + (t >> 5);
  int bg1 = ((t >> 5) << 9) + (t & 31) + ((t >> 5) << 4);
  int qq = t & 1;
  int bg2 = 33 * (t >> 1) + qq;
  dft16_fwd(xr, xi);
  {
    float2 w1 = tw[t];
    TWCHAIN(xr, xi, w1.x, w1.y);
  }
#pragma unroll
  for (int j = 0; j < 16; ++j) lbuf[bs1 + 528 * REV[j]] = xr[j];
  __syncthreads();
#pragma unroll
  for (int m = 0; m < 16; ++m) xr[m] = lbuf[bg1 + 33 * m];
  __syncthreads();
#pragma unroll
  for (int j = 0; j < 16; ++j) lbuf[bs1 + 528 * REV[j]] = xi[j];
  __syncthreads();
#pragma unroll
  for (int m = 0; m < 16; ++m) xi[m] = lbuf[bg1 + 33 * m];
  dft16_fwd(xr, xi);
  {
    float2 w1 = tw[(t & 31) << 4];
    TWCHAIN(xr, xi, w1.x, w1.y);
  }
#pragma unroll
  for (int j = 0; j < 16; ++j) lbuf[bg1 + 33 * REV[j]] = xr[j];
  __syncthreads();
#pragma unroll
  for (int m = 0; m < 16; ++m) xr[m] = lbuf[bg2 + 2 * m];
  __syncthreads();
#pragma unroll
  for (int j = 0; j < 16; ++j) lbuf[bg1 + 33 * REV[j]] = xi[j];
  __syncthreads();
#pragma unroll
  for (int m = 0; m < 16; ++m) xi[m] = lbuf[bg2 + 2 * m];
  dft16_fwd(xr, xi);
  if (qq) {
#pragma unroll
    for (int k = 1; k < 16; ++k) cmul(xr[REV[k]], xi[REV[k]], W32C[k], -W32S[k]);
  }
  float sgn = qq ? -1.f : 1.f;
#pragma unroll
  for (int j = 0; j < 16; ++j) {
    float pr = __shfl_xor(xr[j], 1);
    float pi = __shfl_xor(xi[j], 1);
    xr[j] = sgn * xr[j] + pr;
    xi[j] = sgn * xi[j] + pi;
  }
}

// exact inverse (conjugate twiddles, mirrored); scale 8192 folded into Kst.
// Final dft16 computes only natural outputs 0..7 (the kept samples).
static __device__ __forceinline__ void fft8192_inv(float* xr, float* xi, float* lbuf,
                                                   int t, const float2* __restrict__ tw) {
  REV_INIT;
  int bs1 = t + (t >> 5);
  int bg1 = ((t >> 5) << 9) + (t & 31) + ((t >> 5) << 4);
  int qq = t & 1;
  int bg2 = 33 * (t >> 1) + qq;
  float sgn = qq ? -1.f : 1.f;
#pragma unroll
  for (int j = 0; j < 16; ++j) {
    float pr = __shfl_xor(xr[j], 1);
    float pi = __shfl_xor(xi[j], 1);
    xr[j] = sgn * xr[j] + pr;
    xi[j] = sgn * xi[j] + pi;
  }
  if (qq) {
#pragma unroll
    for (int k = 1; k < 16; ++k) cmul(xr[REV[k]], xi[REV[k]], W32C[k], W32S[k]);
  }
  dft16_inv_t<false>(xr, xi);
#pragma unroll
  for (int m = 0; m < 16; ++m) lbuf[bg2 + 2 * m] = xr[m];
  __syncthreads();
#pragma unroll
  for (int j = 0; j < 16; ++j) xr[j] = lbuf[bg1 + 33 * REV[j]];
  __syncthreads();
#pragma unroll
  for (int m = 0; m < 16; ++m) lbuf[bg2 + 2 * m] = xi[m];
  __syncthreads();
#pragma unroll
  for (int j = 0; j < 16; ++j) xi[j] = lbuf[bg1 + 33 * REV[j]];
  {
    float2 w1 = tw[(t & 31) << 4];
    TWCHAIN(xr, xi, w1.x, -w1.y);
  }
  dft16_inv_t<false>(xr, xi);
#pragma unroll
  for (int m = 0; m < 16; ++m) lbuf[bg1 + 33 * m] = xr[m];
  __syncthreads();
#pragma unroll
  for (int j = 0; j < 16; ++j) xr[j] = lbuf[bs1 + 528 * REV[j]];
  __syncthreads();
#pragma unroll
  for (int m = 0; m < 16; ++m) lbuf[bg1 + 33 * m] = xi[m];
  __syncthreads();
#pragma unroll
  for (int j = 0; j < 16; ++j) xi[j] = lbuf[bs1 + 528 * REV[j]];
  {
    float2 w1 = tw[t];
    TWCHAIN(xr, xi, w1.x, -w1.y);
  }
  dft16_inv_t<true>(xr, xi);
}

// ---------------- setup: build normalized k, twiddles, Wbf ----------------
__global__ void __launch_bounds__(256) gconv_setup(
    const float* __restrict__ kernels,  // [8][1][256][32]
    const float* __restrict__ W_out,    // [256][256]
    float* __restrict__ k_norm,         // [256][4096]
    float2* __restrict__ tw,            // [512]
    unsigned short* __restrict__ Wbf)   // bf16 [256 m][256 h]
{
  int blk = blockIdx.x;
  int tid = threadIdx.x;
  if (blk < 256) {
    int h = blk;
    __shared__ float red[256];
    float val[16];
    float ss = 0.0f;
#pragma unroll
    for (int r = 0; r < 16; ++r) {
      int l = tid + 256 * r;
      int i;
      if (l < 32) i = 0;
      else if (l < 64) i = 1;
      else i = (31 - __clz(l)) - 4;
      int off = (i == 0) ? 0 : (16 << i);
      int s = (i <= 1) ? 1 : (1 << (i - 1));
      float mult = (float)(1 << (7 - i));
      int j = l - off;
      const float* kb = kernels + ((size_t)i * 256 + h) * 32;
      float v;
      if (s == 1) {
        v = kb[j];
      } else {
        float x = ((float)j + 0.5f) / (float)s - 0.5f;
        x = fminf(fmaxf(x, 0.0f), 31.0f);
        float xf = floorf(x);
        int x0 = (int)xf;
        int x1 = min(x0 + 1, 31);
        float w = x - xf;
        v = kb[x0] * (1.0f - w) + kb[x1] * w;
      }
      v *= mult;
      val[r] = v;
      ss += v * v;
    }
    red[tid] = ss;
    __syncthreads();
    for (int o = 128; o > 0; o >>= 1) {
      if (tid < o) red[tid] += red[tid + o];
      __syncthreads();
    }
    float inv = 1.0f / sqrtf(red[0]);
#pragma unroll
    for (int r = 0; r < 16; ++r)
      k_norm[(size_t)h * 4096 + tid + 256 * r] = val[r] * inv;
  } else if (blk < 258) {
    int idx = (blk - 256) * 256 + tid;  // 0..511
    double ang = -6.283185307179586477 * (double)idx / 8192.0;
    tw[idx] = make_float2((float)cos(ang), (float)sin(ang));
  } else {
    int o = (blk - 258) * 256 + tid;    // 0..65535 ; same [m][h] layout as W_out
    Wbf[o] = f2bf(W_out[o]);
  }
}

// ---------------- kernel FFT: K_hat (permuted layout), D and 1/N folded ---
__global__ void __launch_bounds__(512, 4) gconv_kfft(
    const float* __restrict__ k_norm,
    const float* __restrict__ Dvec,
    const float2* __restrict__ tw,
    float2* __restrict__ Kst)           // [256][8192], index h*8192 + t*16 + j
{
  __shared__ float lbuf[8448];
  int h = blockIdx.x;
  int t = threadIdx.x;
  float xr[16], xi[16];
  const float* kn = k_norm + ((size_t)h << 12);
#pragma unroll
  for (int m = 0; m < 8; ++m) { xr[m] = kn[t + (m << 9)]; xi[m] = 0.f; }
#pragma unroll
  for (int m = 8; m < 16; ++m) { xr[m] = 0.f; xi[m] = 0.f; }
  fft8192_fwd(xr, xi, lbuf, t, tw);
  float Dh = Dvec[h];
  const float sc = 1.0f / 8192.0f;
  float2* out = Kst + ((size_t)h << 13) + (t << 4);
#pragma unroll
  for (int j = 0; j < 16; ++j)
    out[j] = make_float2((xr[j] + Dh) * sc, xi[j] * sc);
}

// ---------------- main: fwd FFT (b-pair packed), multiply, inv FFT, gelu --
__global__ void __launch_bounds__(512, 4) gconv_main(
    const float* __restrict__ u,
    const float2* __restrict__ tw,
    const float2* __restrict__ Kst,
    unsigned short* __restrict__ g)     // bf16 [16][256][4096]
{
  __shared__ float lbuf[8448];
  int blk = blockIdx.x;
  int h = blk & 255;
  int pb = blk >> 8;                    // 0..7 ; batches pb and pb+8
  int t = threadIdx.x;
  const float* u0 = u + ((size_t)(pb * 256 + h) << 12);
  const float* u1 = u + ((size_t)((pb + 8) * 256 + h) << 12);
  float xr[16], xi[16];
#pragma unroll
  for (int m = 0; m < 8; ++m) { xr[m] = u0[t + (m << 9)]; xi[m] = u1[t + (m << 9)]; }
#pragma unroll
  for (int m = 8; m < 16; ++m) { xr[m] = 0.f; xi[m] = 0.f; }
  fft8192_fwd(xr, xi, lbuf, t, tw);
  const float2* kr = Kst + ((size_t)h << 13) + (t << 4);
#pragma unroll
  for (int j = 0; j < 16; ++j) {
    float2 kv = kr[j];
    cmul(xr[j], xi[j], kv.x, kv.y);
  }
  fft8192_inv(xr, xi, lbuf, t, tw);
  unsigned short* g0 = g + ((size_t)(pb * 256 + h) << 12) + t;
  unsigned short* g1 = g + ((size_t)((pb + 8) * 256 + h) << 12) + t;
#pragma unroll
  for (int m = 0; m < 8; ++m) {
    g0[m << 9] = f2bf(gelu_t(xr[m]));
    g1[m << 9] = f2bf(gelu_t(xi[m]));
  }
}

// -------- output projection (MFMA): out[b][m][l] = sum_h W[m][h] g[b][h][l] + b[m]
__global__ void __launch_bounds__(256) gconv_out(
    const unsigned short* __restrict__ g,   // bf16 [16][256][4096]
    const unsigned short* __restrict__ Wbf, // bf16 [256 m][256 h]
    const float* __restrict__ b_out,        // [256]
    float* __restrict__ out)                // [16][256][4096]
{
  __shared__ unsigned short As[128][40];    // [m][k], 80B rows (16B aligned)
  __shared__ unsigned short Bs[32][132];    // [k][l], 264B rows (bank-staggered)
  int l0 = blockIdx.x * 128;
  int m0 = blockIdx.y * 128;
  int b  = blockIdx.z;
  int tid = threadIdx.x;
  int lane = tid & 63, wid = tid >> 6;
  int wm = (wid >> 1) * 64, wl = (wid & 1) * 64;  // wave quadrant
  int lhi = lane >> 4, llo = lane & 15;
  f32x4 acc[4][4];
#pragma unroll
  for (int a = 0; a < 4; ++a)
#pragma unroll
    for (int c = 0; c < 4; ++c) acc[a][c] = (f32x4){0.f, 0.f, 0.f, 0.f};

  for (int ks = 0; ks < 8; ++ks) {
    int k0 = ks * 32;
#pragma unroll
    for (int i = 0; i < 2; ++i) {
      int idx = tid + i * 256;
      int m = idx >> 2, c = idx & 3;           // A: 128 rows x 4 chunks of 8
      *(uint4*)&As[m][c * 8] =
          *(const uint4*)(Wbf + ((size_t)(m0 + m) << 8) + k0 + c * 8);
      int k = idx >> 4, cc = idx & 15;         // B: 32 rows x 16 chunks of 8
      const unsigned short* gp =
          g + ((size_t)(b * 256 + k0 + k) << 12) + l0 + cc * 8;
      ((uint2*)&Bs[k][cc * 8])[0] = ((const uint2*)gp)[0];
      ((uint2*)&Bs[k][cc * 8])[1] = ((const uint2*)gp)[1];
    }
    __syncthreads();
    int kk = lhi * 8;
    bf16x8 af[4], bfr[4];
#pragma unroll
    for (int f = 0; f < 4; ++f)
      af[f] = *(bf16x8*)&As[wm + f * 16 + llo][kk];
#pragma unroll
    for (int f = 0; f < 4; ++f) {
      bf16x8 v;
#pragma unroll
      for (int j = 0; j < 8; ++j)
        v[j] = (short)Bs[kk + j][wl + f * 16 + llo];
      bfr[f] = v;
    }
#pragma unroll
    for (int fm = 0; fm < 4; ++fm)
#pragma unroll
      for (int fl = 0; fl < 4; ++fl)
        acc[fm][fl] = __builtin_amdgcn_mfma_f32_16x16x32_bf16(
            af[fm], bfr[fl], acc[fm][fl], 0, 0, 0);
    __syncthreads();
  }
#pragma unroll
  for (int fm = 0; fm < 4; ++fm) {
#pragma unroll
    for (int r = 0; r < 4; ++r) {
      int m = m0 + wm + fm * 16 + lhi * 4 + r;
      float bias = b_out[m];
      float* op = out + ((size_t)(b * 256 + m) << 12) + l0 + wl + llo;
#pragma unroll
      for (int fl = 0; fl < 4; ++fl)
        op[fl * 16] = acc[fm][fl][r] + bias;
    }
  }
}

extern "C" void kernel_launch(void* const* d_in, const int* in_sizes, int n_in,
                              void* d_out, int out_size, void* d_ws, size_t ws_size,
                              hipStream_t stream) {
  (void)in_sizes; (void)n_in; (void)out_size; (void)ws_size;
  const float* u       = (const float*)d_in[0];
  const float* kernels = (const float*)d_in[1];
  const float* Dvec    = (const float*)d_in[2];
  const float* W_out   = (const float*)d_in[3];
  const float* b_out   = (const float*)d_in[4];
  float* out = (float*)d_out;
  char* ws = (char*)d_ws;

  float*  k_norm = (float*)(ws);
  float2* tw     = (float2*)(ws + (4u << 20));
  unsigned short* Wbf = (unsigned short*)(ws + (4u << 20) + (128u << 10));
  float2* Kst    = (float2*)(ws + (8u << 20));
  unsigned short* g = (unsigned short*)(ws + (24u << 20));

  gconv_setup<<<514, 256, 0, stream>>>(kernels, W_out, k_norm, tw, Wbf);
  gconv_kfft<<<256, 512, 0, stream>>>(k_norm, Dvec, tw, Kst);
  gconv_main<<<2048, 512, 0, stream>>>(u, tw, Kst, g);
  dim3 gd(32, 2, 16);
  gconv_out<<<gd, 256, 0, stream>>>(g, Wbf, b_out, out);
}